// Round 2
// baseline (230.494 us; speedup 1.0000x reference)
//
#include <hip/hip_runtime.h>
#include <cstdint>

typedef unsigned short u16;
typedef __attribute__((ext_vector_type(8))) short short8;   // 8 x bf16 fragment
typedef __attribute__((ext_vector_type(4))) float f32x4;

__device__ __forceinline__ u16 f2bf(float f) {
  union { float f; uint32_t u; } c; c.f = f;
  return (u16)((c.u + 0x7FFFu + ((c.u >> 16) & 1u)) >> 16);
}

// ---------- fp32 -> bf16 elementwise (4 per thread) ----------
__global__ __launch_bounds__(256) void conv_bf16(const float* __restrict__ in,
                                                 u16* __restrict__ out, int n4) {
  int i = blockIdx.x * 256 + threadIdx.x;
  if (i >= n4) return;
  float4 v = ((const float4*)in)[i];
  ((ushort4*)out)[i] = make_ushort4(f2bf(v.x), f2bf(v.y), f2bf(v.z), f2bf(v.w));
}

// ---------- transpose + convert: in [K][N] f32 -> out [N][K] bf16 ----------
__global__ __launch_bounds__(256) void transpose_conv(const float* __restrict__ in,
                                                      u16* __restrict__ out, int K, int N) {
  __shared__ float tile[64][65];
  int n0 = blockIdx.x * 64, k0 = blockIdx.y * 64;
  int t = threadIdx.x;
  int a = t & 63, b4 = t >> 6;
#pragma unroll
  for (int j = 0; j < 16; ++j) {
    int kk = j * 4 + b4;
    tile[kk][a] = in[(size_t)(k0 + kk) * N + n0 + a];
  }
  __syncthreads();
#pragma unroll
  for (int j = 0; j < 16; ++j) {
    int nn = j * 4 + b4;
    out[(size_t)(n0 + nn) * K + k0 + a] = f2bf(tile[a][nn]);
  }
}

// ---------- bf16 GEMM: C[M][N] (f32,+bias) = A[M][K] * Bt[N][K]^T ----------
// 128x128 tile, BK=32, 4 waves (2x2), 16x16x32 MFMA, global_load_lds staging.
__global__ __launch_bounds__(256, 2) void gemm_bt(const u16* __restrict__ A,
                                                  const u16* __restrict__ Bt,
                                                  float* __restrict__ C,
                                                  const float* __restrict__ bias,
                                                  int M, int N, int K) {
  __shared__ alignas(16) u16 As[128 * 32];
  __shared__ alignas(16) u16 Bs[128 * 32];
  int nb = N >> 7;
  int m0 = (blockIdx.x / nb) << 7;
  int n0 = (blockIdx.x % nb) << 7;
  int tid = threadIdx.x;
  int w = tid >> 6, lane = tid & 63;
  int wr = w >> 1, wc = w & 1;
  int fr = lane & 15, hi = lane >> 4, fk = hi * 8;
  f32x4 acc[4][4] = {};
  for (int kt = 0; kt < K; kt += 32) {
#pragma unroll
    for (int b = 0; b < 2; ++b) {
      int chunk = b * 256 + tid;
      int r = chunk >> 2, c = chunk & 3;
      const u16* ga = A + (size_t)(m0 + r) * K + kt + c * 8;
      const u16* gb = Bt + (size_t)(n0 + r) * K + kt + c * 8;
      u16* la = As + (size_t)(b * 256 + w * 64) * 8;   // wave-uniform base
      u16* lb = Bs + (size_t)(b * 256 + w * 64) * 8;
      __builtin_amdgcn_global_load_lds((const __attribute__((address_space(1))) void*)ga,
                                       (__attribute__((address_space(3))) void*)la, 16, 0, 0);
      __builtin_amdgcn_global_load_lds((const __attribute__((address_space(1))) void*)gb,
                                       (__attribute__((address_space(3))) void*)lb, 16, 0, 0);
    }
    __syncthreads();
    short8 af[4], bfr[4];
#pragma unroll
    for (int m = 0; m < 4; ++m) af[m] = *(const short8*)&As[(wr * 64 + m * 16 + fr) * 32 + fk];
#pragma unroll
    for (int n = 0; n < 4; ++n) bfr[n] = *(const short8*)&Bs[(wc * 64 + n * 16 + fr) * 32 + fk];
#pragma unroll
    for (int m = 0; m < 4; ++m)
#pragma unroll
      for (int n = 0; n < 4; ++n)
        acc[m][n] = __builtin_amdgcn_mfma_f32_16x16x32_bf16(af[m], bfr[n], acc[m][n], 0, 0, 0);
    __syncthreads();
  }
#pragma unroll
  for (int m = 0; m < 4; ++m) {
#pragma unroll
    for (int n = 0; n < 4; ++n) {
      int gcol = n0 + wc * 64 + n * 16 + fr;
      float bv = bias ? bias[gcol] : 0.0f;
#pragma unroll
      for (int r = 0; r < 4; ++r) {
        int grow = m0 + wr * 64 + m * 16 + hi * 4 + r;
        C[(size_t)grow * N + gcol] = acc[m][n][r] + bv;
      }
    }
  }
}

// ---------- QKV postprocess: bias + RMSNorm + RoPE + layout [head][t][64] bf16 ----------
// one wave per (t, head); heads 0..31 = Q, 32..39 = K, 40..47 = V
__global__ __launch_bounds__(256) void qkv_post(const float* __restrict__ qkv,
    const float* __restrict__ wq_b, const float* __restrict__ wk_b, const float* __restrict__ wv_b,
    const float* __restrict__ qn_w, const float* __restrict__ kn_w,
    const float* __restrict__ fc, const float* __restrict__ fs,
    u16* __restrict__ Qg, u16* __restrict__ Kg, u16* __restrict__ Vg) {
  int gid = blockIdx.x * 256 + threadIdx.x;
  int wave = gid >> 6, d = gid & 63;
  int t = wave / 48, hh = wave % 48;
  float v;
  if (hh < 32)       v = qkv[(size_t)t * 3072 + hh * 64 + d] + wq_b[hh * 64 + d];
  else if (hh < 40)  v = qkv[(size_t)t * 3072 + 2048 + (hh - 32) * 64 + d] + wk_b[(hh - 32) * 64 + d];
  else               v = qkv[(size_t)t * 3072 + 2560 + (hh - 40) * 64 + d] + wv_b[(hh - 40) * 64 + d];
  if (hh < 40) {
    float sq = v * v;
#pragma unroll
    for (int off = 32; off >= 1; off >>= 1) sq += __shfl_xor(sq, off);
    float rr = rsqrtf(sq * (1.0f / 64.0f) + 1e-5f);
    float wn = (hh < 32) ? qn_w[d] : kn_w[d];
    v = v * rr * wn;
    float part = __shfl_xor(v, 1);
    float c = fc[t * 32 + (d >> 1)];
    float s = fs[t * 32 + (d >> 1)];
    v = (d & 1) ? (part * s + v * c) : (v * c - part * s);
  }
  u16 bv = f2bf(v);
  if (hh < 32)       Qg[((size_t)hh * 2048 + t) * 64 + d] = bv;
  else if (hh < 40)  Kg[((size_t)(hh - 32) * 2048 + t) * 64 + d] = bv;
  else               Vg[((size_t)(hh - 40) * 2048 + t) * 64 + d] = bv;
}

// ---------- causal GQA flash attention ----------
// grid: 1024 blocks, bid = qt*32 + h. 4 waves x 16 q-rows, K-tile 64, D=64.
__global__ __launch_bounds__(256, 2) void attn_kernel(const u16* __restrict__ Qg,
                                                      const u16* __restrict__ Kg,
                                                      const u16* __restrict__ Vg,
                                                      u16* __restrict__ att) {
  __shared__ alignas(16) u16 Ks[64 * 72];       // [key][d], +8 pad
  __shared__ alignas(16) u16 Vs[64 * 72];       // [d][key], +8 pad
  __shared__ alignas(16) u16 Ps[4][16 * 72];    // per-wave P tile [qrow][key]
  int h = blockIdx.x & 31;
  int qt = blockIdx.x >> 5;
  int kvh = h >> 2;
  int tid = threadIdx.x, w = tid >> 6, lane = tid & 63;
  int fr = lane & 15, hi = lane >> 4, fk = hi * 8;
  const u16* qbase = Qg + ((size_t)h * 2048 + qt * 64 + w * 16 + fr) * 64;
  short8 qf0 = *(const short8*)(qbase + fk);
  short8 qf1 = *(const short8*)(qbase + 32 + fk);
  f32x4 o[4] = {};
  float m[4], l[4];
#pragma unroll
  for (int r = 0; r < 4; ++r) { m[r] = -1e30f; l[r] = 0.0f; }
  int vkey = tid & 63, vd0 = (tid >> 6) * 16;
  for (int kt = 0; kt <= qt; ++kt) {
    // stage K tile [64][64] (row-major, padded)
#pragma unroll
    for (int b = 0; b < 2; ++b) {
      int chunk = b * 256 + tid;
      int key = chunk >> 3, c = chunk & 7;
      *(short8*)&Ks[key * 72 + c * 8] =
          *(const short8*)(Kg + ((size_t)kvh * 2048 + kt * 64 + key) * 64 + c * 8);
    }
    // stage V transposed: Vs[d][key]
    {
      const u16* g = Vg + ((size_t)kvh * 2048 + kt * 64 + vkey) * 64 + vd0;
      short8 v0 = *(const short8*)g;
      short8 v1 = *(const short8*)(g + 8);
#pragma unroll
      for (int j = 0; j < 8; ++j) Vs[(vd0 + j) * 72 + vkey] = (u16)v0[j];
#pragma unroll
      for (int j = 0; j < 8; ++j) Vs[(vd0 + 8 + j) * 72 + vkey] = (u16)v1[j];
    }
    __syncthreads();
    // S = Q K^T  (rows: q, cols: key)
    f32x4 s4[4] = {};
#pragma unroll
    for (int g = 0; g < 4; ++g) {
      short8 b0 = *(const short8*)&Ks[(g * 16 + fr) * 72 + fk];
      short8 b1 = *(const short8*)&Ks[(g * 16 + fr) * 72 + 32 + fk];
      s4[g] = __builtin_amdgcn_mfma_f32_16x16x32_bf16(qf0, b0, s4[g], 0, 0, 0);
      s4[g] = __builtin_amdgcn_mfma_f32_16x16x32_bf16(qf1, b1, s4[g], 0, 0, 0);
    }
    int qr0 = qt * 64 + w * 16 + hi * 4;
    int kc0 = kt * 64 + fr;
    // online softmax (row stats live in the 16 lanes of each hi-group)
#pragma unroll
    for (int r = 0; r < 4; ++r) {
      float sv[4];
      float tm = -1e30f;
#pragma unroll
      for (int g = 0; g < 4; ++g) {
        float x = s4[g][r] * 0.125f;
        if (kc0 + g * 16 > qr0 + r) x = -1e30f;   // causal
        sv[g] = x;
        tm = fmaxf(tm, x);
      }
#pragma unroll
      for (int off = 1; off < 16; off <<= 1) tm = fmaxf(tm, __shfl_xor(tm, off));
      float mn = fmaxf(m[r], tm);
      float alpha = __expf(m[r] - mn);
      float rsum = 0.0f;
#pragma unroll
      for (int g = 0; g < 4; ++g) {
        float pe = __expf(sv[g] - mn);
        rsum += pe;
        Ps[w][(hi * 4 + r) * 72 + g * 16 + fr] = f2bf(pe);
      }
#pragma unroll
      for (int off = 1; off < 16; off <<= 1) rsum += __shfl_xor(rsum, off);
      l[r] = l[r] * alpha + rsum;
      m[r] = mn;
#pragma unroll
      for (int g2 = 0; g2 < 4; ++g2) o[g2][r] *= alpha;
    }
    asm volatile("s_waitcnt lgkmcnt(0)" ::: "memory");  // P writes land (wave-local)
    // O += P V
    short8 pa0 = *(const short8*)&Ps[w][fr * 72 + fk];
    short8 pa1 = *(const short8*)&Ps[w][fr * 72 + 32 + fk];
#pragma unroll
    for (int g2 = 0; g2 < 4; ++g2) {
      short8 vb0 = *(const short8*)&Vs[(g2 * 16 + fr) * 72 + fk];
      short8 vb1 = *(const short8*)&Vs[(g2 * 16 + fr) * 72 + 32 + fk];
      o[g2] = __builtin_amdgcn_mfma_f32_16x16x32_bf16(pa0, vb0, o[g2], 0, 0, 0);
      o[g2] = __builtin_amdgcn_mfma_f32_16x16x32_bf16(pa1, vb1, o[g2], 0, 0, 0);
    }
    __syncthreads();
  }
#pragma unroll
  for (int r = 0; r < 4; ++r) {
    float inv = 1.0f / l[r];
    size_t rowoff = (size_t)(qt * 64 + w * 16 + hi * 4 + r) * 2048 + h * 64;
#pragma unroll
    for (int g2 = 0; g2 < 4; ++g2)
      att[rowoff + g2 * 16 + fr] = f2bf(o[g2][r] * inv);
  }
}

extern "C" void kernel_launch(void* const* d_in, const int* in_sizes, int n_in,
                              void* d_out, int out_size, void* d_ws, size_t ws_size,
                              hipStream_t stream) {
  const float* x    = (const float*)d_in[0];
  const float* fc   = (const float*)d_in[1];
  const float* fs   = (const float*)d_in[2];
  // d_in[3] = mask (causal, regenerated in-kernel)
  const float* wq   = (const float*)d_in[4];
  const float* wq_b = (const float*)d_in[5];
  const float* wk   = (const float*)d_in[6];
  const float* wk_b = (const float*)d_in[7];
  const float* wv   = (const float*)d_in[8];
  const float* wv_b = (const float*)d_in[9];
  const float* wo   = (const float*)d_in[10];
  const float* wo_b = (const float*)d_in[11];
  const float* qn   = (const float*)d_in[12];
  const float* kn   = (const float*)d_in[13];
  float* out = (float*)d_out;

  char* ws = (char*)d_ws;
  u16*  xb    = (u16*)(ws);                          //  8 MB  x bf16 [2048][2048]
  u16*  wqkvT = (u16*)(ws + (size_t)(8  << 20));     // 12 MB  [3072][2048] bf16
  u16*  woT   = (u16*)(ws + (size_t)(20 << 20));     //  8 MB  [2048][2048] bf16
  float* qkv  = (float*)(ws + (size_t)(28 << 20));   // 24 MB  [2048][3072] f32
  u16*  Qg    = (u16*)(ws + (size_t)(52 << 20));     //  8 MB  [32][2048][64]
  u16*  Kg    = (u16*)(ws + (size_t)(60 << 20));     //  2 MB  [8][2048][64]
  u16*  Vg    = (u16*)(ws + (size_t)(62 << 20));     //  2 MB  [8][2048][64]
  u16*  att   = (u16*)(ws + (size_t)(64 << 20));     //  8 MB  [2048][2048]

  conv_bf16<<<4096, 256, 0, stream>>>(x, xb, 1048576);
  transpose_conv<<<dim3(32, 32), 256, 0, stream>>>(wq, wqkvT, 2048, 2048);
  transpose_conv<<<dim3(8, 32),  256, 0, stream>>>(wk, wqkvT + (size_t)2048 * 2048, 2048, 512);
  transpose_conv<<<dim3(8, 32),  256, 0, stream>>>(wv, wqkvT + (size_t)2560 * 2048, 2048, 512);
  transpose_conv<<<dim3(32, 32), 256, 0, stream>>>(wo, woT, 2048, 2048);
  gemm_bt<<<16 * 24, 256, 0, stream>>>(xb, wqkvT, qkv, (const float*)nullptr, 2048, 3072, 2048);
  qkv_post<<<24576, 256, 0, stream>>>(qkv, wq_b, wk_b, wv_b, qn, kn, fc, fs, Qg, Kg, Vg);
  attn_kernel<<<1024, 256, 0, stream>>>(Qg, Kg, Vg, att);
  gemm_bt<<<16 * 16, 256, 0, stream>>>(att, woT, out, wo_b, 2048, 2048, 2048);
}

// Round 3
// 221.686 us; speedup vs baseline: 1.0397x; 1.0397x over previous
//
#include <hip/hip_runtime.h>
#include <cstdint>

typedef unsigned short u16;
typedef __attribute__((ext_vector_type(8))) short short8;   // 8 x bf16 fragment
typedef __attribute__((ext_vector_type(4))) float f32x4;

__device__ __forceinline__ u16 f2bf(float f) {
  union { float f; uint32_t u; } c; c.f = f;
  return (u16)((c.u + 0x7FFFu + ((c.u >> 16) & 1u)) >> 16);
}

// ---------- fp32 -> bf16 elementwise (4 per thread) ----------
__global__ __launch_bounds__(256) void conv_bf16(const float* __restrict__ in,
                                                 u16* __restrict__ out, int n4) {
  int i = blockIdx.x * 256 + threadIdx.x;
  if (i >= n4) return;
  float4 v = ((const float4*)in)[i];
  ((ushort4*)out)[i] = make_ushort4(f2bf(v.x), f2bf(v.y), f2bf(v.z), f2bf(v.w));
}

// ---------- transpose + convert: in [K][N] f32 -> out [N][K] bf16 ----------
__global__ __launch_bounds__(256) void transpose_conv(const float* __restrict__ in,
                                                      u16* __restrict__ out, int K, int N) {
  __shared__ float tile[64][65];
  int n0 = blockIdx.x * 64, k0 = blockIdx.y * 64;
  int t = threadIdx.x;
  int a = t & 63, b4 = t >> 6;
#pragma unroll
  for (int j = 0; j < 16; ++j) {
    int kk = j * 4 + b4;
    tile[kk][a] = in[(size_t)(k0 + kk) * N + n0 + a];
  }
  __syncthreads();
#pragma unroll
  for (int j = 0; j < 16; ++j) {
    int nn = j * 4 + b4;
    out[(size_t)(n0 + nn) * K + k0 + a] = f2bf(tile[a][nn]);
  }
}

// ---------- bf16 GEMM: C[M][N] (f32,+bias) = A[M][K] * Bt[N][K]^T ----------
// 128x128 tile, BK=32, 4 waves (2x2), 16x16x32 MFMA, global_load_lds staging.
__global__ __launch_bounds__(256, 2) void gemm_bt(const u16* __restrict__ A,
                                                  const u16* __restrict__ Bt,
                                                  float* __restrict__ C,
                                                  const float* __restrict__ bias,
                                                  int M, int N, int K) {
  __shared__ alignas(16) u16 As[128 * 32];
  __shared__ alignas(16) u16 Bs[128 * 32];
  int nb = N >> 7;
  int m0 = (blockIdx.x / nb) << 7;
  int n0 = (blockIdx.x % nb) << 7;
  int tid = threadIdx.x;
  int w = tid >> 6, lane = tid & 63;
  int wr = w >> 1, wc = w & 1;
  int fr = lane & 15, hi = lane >> 4, fk = hi * 8;
  f32x4 acc[4][4] = {};
  for (int kt = 0; kt < K; kt += 32) {
#pragma unroll
    for (int b = 0; b < 2; ++b) {
      int chunk = b * 256 + tid;
      int r = chunk >> 2, c = chunk & 3;
      const u16* ga = A + (size_t)(m0 + r) * K + kt + c * 8;
      const u16* gb = Bt + (size_t)(n0 + r) * K + kt + c * 8;
      u16* la = As + (size_t)(b * 256 + w * 64) * 8;   // wave-uniform base
      u16* lb = Bs + (size_t)(b * 256 + w * 64) * 8;
      __builtin_amdgcn_global_load_lds((const __attribute__((address_space(1))) void*)ga,
                                       (__attribute__((address_space(3))) void*)la, 16, 0, 0);
      __builtin_amdgcn_global_load_lds((const __attribute__((address_space(1))) void*)gb,
                                       (__attribute__((address_space(3))) void*)lb, 16, 0, 0);
    }
    __syncthreads();
    short8 af[4], bfr[4];
#pragma unroll
    for (int m = 0; m < 4; ++m) af[m] = *(const short8*)&As[(wr * 64 + m * 16 + fr) * 32 + fk];
#pragma unroll
    for (int n = 0; n < 4; ++n) bfr[n] = *(const short8*)&Bs[(wc * 64 + n * 16 + fr) * 32 + fk];
#pragma unroll
    for (int m = 0; m < 4; ++m)
#pragma unroll
      for (int n = 0; n < 4; ++n)
        acc[m][n] = __builtin_amdgcn_mfma_f32_16x16x32_bf16(af[m], bfr[n], acc[m][n], 0, 0, 0);
    __syncthreads();
  }
#pragma unroll
  for (int m = 0; m < 4; ++m) {
#pragma unroll
    for (int n = 0; n < 4; ++n) {
      int gcol = n0 + wc * 64 + n * 16 + fr;
      float bv = bias ? bias[gcol] : 0.0f;
#pragma unroll
      for (int r = 0; r < 4; ++r) {
        int grow = m0 + wr * 64 + m * 16 + hi * 4 + r;
        C[(size_t)grow * N + gcol] = acc[m][n][r] + bv;
      }
    }
  }
}

// ---------- QKV postprocess: bias + RMSNorm + RoPE + layout [head][t][64] bf16 ----------
// one wave per (t, head); heads 0..31 = Q, 32..39 = K, 40..47 = V
__global__ __launch_bounds__(256) void qkv_post(const float* __restrict__ qkv,
    const float* __restrict__ wq_b, const float* __restrict__ wk_b, const float* __restrict__ wv_b,
    const float* __restrict__ qn_w, const float* __restrict__ kn_w,
    const float* __restrict__ fc, const float* __restrict__ fs,
    u16* __restrict__ Qg, u16* __restrict__ Kg, u16* __restrict__ Vg) {
  int gid = blockIdx.x * 256 + threadIdx.x;
  int wave = gid >> 6, d = gid & 63;
  int t = wave / 48, hh = wave % 48;
  float v;
  if (hh < 32)       v = qkv[(size_t)t * 3072 + hh * 64 + d] + wq_b[hh * 64 + d];
  else if (hh < 40)  v = qkv[(size_t)t * 3072 + 2048 + (hh - 32) * 64 + d] + wk_b[(hh - 32) * 64 + d];
  else               v = qkv[(size_t)t * 3072 + 2560 + (hh - 40) * 64 + d] + wv_b[(hh - 40) * 64 + d];
  if (hh < 40) {
    float sq = v * v;
#pragma unroll
    for (int off = 32; off >= 1; off >>= 1) sq += __shfl_xor(sq, off);
    float rr = rsqrtf(sq * (1.0f / 64.0f) + 1e-5f);
    float wn = (hh < 32) ? qn_w[d] : kn_w[d];
    v = v * rr * wn;
    float part = __shfl_xor(v, 1);
    float c = fc[t * 32 + (d >> 1)];
    float s = fs[t * 32 + (d >> 1)];
    v = (d & 1) ? (part * s + v * c) : (v * c - part * s);
  }
  u16 bv = f2bf(v);
  if (hh < 32)       Qg[((size_t)hh * 2048 + t) * 64 + d] = bv;
  else if (hh < 40)  Kg[((size_t)(hh - 32) * 2048 + t) * 64 + d] = bv;
  else               Vg[((size_t)(hh - 40) * 2048 + t) * 64 + d] = bv;
}

// ---------- causal GQA flash attention (v2) ----------
// grid 1024; balanced qt remap; XOR-swizzled K/V LDS; reg double-buffered staging.
__global__ __launch_bounds__(256, 2) void attn_kernel(const u16* __restrict__ Qg,
                                                      const u16* __restrict__ Kg,
                                                      const u16* __restrict__ Vg,
                                                      u16* __restrict__ att) {
  __shared__ alignas(16) u16 Ks[64 * 64];       // [key][d], XOR-swizzled rows
  __shared__ alignas(16) u16 Vs[64 * 64];       // [d][key], XOR-swizzled rows
  __shared__ alignas(16) u16 Ps[4][16 * 72];    // per-wave P tile [qrow][key], +8 pad
  char* KsB = (char*)Ks;
  char* VsB = (char*)Vs;

  // balanced remap: each CU's round-robin set {q0,15-q0,16+q0,31-q0} sums uniform
  int bid = blockIdx.x;
  int grp = bid >> 8, idx = bid & 255;
  int q0 = idx >> 5, h = idx & 31;
  int qt = (grp == 0) ? q0 : (grp == 1) ? 15 - q0 : (grp == 2) ? 16 + q0 : 31 - q0;
  int kvh = h >> 2;

  int tid = threadIdx.x, w = tid >> 6, lane = tid & 63;
  int fr = lane & 15, hi = lane >> 4, fk = hi * 8;
  const u16* qbase = Qg + ((size_t)h * 2048 + qt * 64 + w * 16 + fr) * 64;
  short8 qf0 = *(const short8*)(qbase + fk);
  short8 qf1 = *(const short8*)(qbase + 32 + fk);
  f32x4 o[4] = {};
  float m[4], l[4];
#pragma unroll
  for (int r = 0; r < 4; ++r) { m[r] = -1e30f; l[r] = 0.0f; }

  // staging thread mapping
  int key0 = tid >> 3, c0 = tid & 7;                 // K chunk b=0: keys 0..31
  int kp = tid & 31, dg = tid >> 5, d0v = dg * 8;    // V: key pair 2kp,2kp+1, d rows d0v..d0v+7
  const u16* Kbase = Kg + (size_t)kvh * 2048 * 64;
  const u16* Vbase = Vg + (size_t)kvh * 2048 * 64;

  auto stage_load = [&](int kt2, short8& k0, short8& k1, short8& v0, short8& v1) {
    const u16* kb = Kbase + (size_t)kt2 * 64 * 64;
    k0 = *(const short8*)(kb + key0 * 64 + c0 * 8);
    k1 = *(const short8*)(kb + (32 + key0) * 64 + c0 * 8);
    const u16* vb = Vbase + (size_t)kt2 * 64 * 64 + (size_t)(2 * kp) * 64 + d0v;
    v0 = *(const short8*)vb;
    v1 = *(const short8*)(vb + 64);
  };
  auto stage_write = [&](short8 k0, short8 k1, short8 v0, short8 v1) {
    int offA = (key0 * 128 + c0 * 16) ^ ((key0 & 7) << 4);
    int offB = ((32 + key0) * 128 + c0 * 16) ^ ((key0 & 7) << 4);   // (32+key0)&7 == key0&7
    *(short8*)(KsB + offA) = k0;
    *(short8*)(KsB + offB) = k1;
#pragma unroll
    for (int j = 0; j < 8; ++j) {
      uint32_t pk = (uint32_t)(u16)v0[j] | ((uint32_t)(u16)v1[j] << 16);
      int d = d0v + j;
      int off = (d * 128 + kp * 4) ^ ((j & 7) << 4);   // d&7 == j
      *(uint32_t*)(VsB + off) = pk;
    }
  };

  short8 kA0, kA1, vA0, vA1, kB0, kB1, vB0, vB1;
  stage_load(0, kA0, kA1, vA0, vA1);

  int swzr = (fr & 7) << 4;   // row-XOR for fragment reads (row&7 == fr&7)
  for (int kt = 0; kt <= qt; ++kt) {
    if ((kt & 1) == 0) stage_write(kA0, kA1, vA0, vA1);
    else               stage_write(kB0, kB1, vB0, vB1);
    __syncthreads();
    if (kt < qt) {   // prefetch next tile into the other reg set; lands under compute
      if ((kt & 1) == 0) stage_load(kt + 1, kB0, kB1, vB0, vB1);
      else               stage_load(kt + 1, kA0, kA1, vA0, vA1);
    }
    // S = Q K^T  (rows: q, cols: key)
    f32x4 s4[4] = {};
#pragma unroll
    for (int g = 0; g < 4; ++g) {
      int rb = (g * 16 + fr) * 128;
      short8 b0 = *(const short8*)(KsB + ((rb + hi * 16) ^ swzr));
      short8 b1 = *(const short8*)(KsB + ((rb + 64 + hi * 16) ^ swzr));
      s4[g] = __builtin_amdgcn_mfma_f32_16x16x32_bf16(qf0, b0, s4[g], 0, 0, 0);
      s4[g] = __builtin_amdgcn_mfma_f32_16x16x32_bf16(qf1, b1, s4[g], 0, 0, 0);
    }
    int qr0 = qt * 64 + w * 16 + hi * 4;
    int kc0 = kt * 64 + fr;
    // online softmax (row stats live in the 16 lanes of each hi-group)
#pragma unroll
    for (int r = 0; r < 4; ++r) {
      float sv[4];
      float tm = -1e30f;
#pragma unroll
      for (int g = 0; g < 4; ++g) {
        float x = s4[g][r] * 0.125f;
        if (kc0 + g * 16 > qr0 + r) x = -1e30f;   // causal
        sv[g] = x;
        tm = fmaxf(tm, x);
      }
#pragma unroll
      for (int off = 1; off < 16; off <<= 1) tm = fmaxf(tm, __shfl_xor(tm, off));
      float mn = fmaxf(m[r], tm);
      float alpha = __expf(m[r] - mn);
      float rsum = 0.0f;
#pragma unroll
      for (int g = 0; g < 4; ++g) {
        float pe = __expf(sv[g] - mn);
        rsum += pe;
        Ps[w][(hi * 4 + r) * 72 + g * 16 + fr] = f2bf(pe);
      }
#pragma unroll
      for (int off = 1; off < 16; off <<= 1) rsum += __shfl_xor(rsum, off);
      l[r] = l[r] * alpha + rsum;
      m[r] = mn;
#pragma unroll
      for (int g2 = 0; g2 < 4; ++g2) o[g2][r] *= alpha;
    }
    asm volatile("s_waitcnt lgkmcnt(0)" ::: "memory");  // P writes land (wave-local)
    // O += P V
    short8 pa0 = *(const short8*)&Ps[w][fr * 72 + fk];
    short8 pa1 = *(const short8*)&Ps[w][fr * 72 + 32 + fk];
#pragma unroll
    for (int g2 = 0; g2 < 4; ++g2) {
      int rb = (g2 * 16 + fr) * 128;
      short8 vb0 = *(const short8*)(VsB + ((rb + hi * 16) ^ swzr));
      short8 vb1 = *(const short8*)(VsB + ((rb + 64 + hi * 16) ^ swzr));
      o[g2] = __builtin_amdgcn_mfma_f32_16x16x32_bf16(pa0, vb0, o[g2], 0, 0, 0);
      o[g2] = __builtin_amdgcn_mfma_f32_16x16x32_bf16(pa1, vb1, o[g2], 0, 0, 0);
    }
    __syncthreads();
  }
#pragma unroll
  for (int r = 0; r < 4; ++r) {
    float inv = 1.0f / l[r];
    size_t rowoff = (size_t)(qt * 64 + w * 16 + hi * 4 + r) * 2048 + h * 64;
#pragma unroll
    for (int g2 = 0; g2 < 4; ++g2)
      att[rowoff + g2 * 16 + fr] = f2bf(o[g2][r] * inv);
  }
}

extern "C" void kernel_launch(void* const* d_in, const int* in_sizes, int n_in,
                              void* d_out, int out_size, void* d_ws, size_t ws_size,
                              hipStream_t stream) {
  const float* x    = (const float*)d_in[0];
  const float* fc   = (const float*)d_in[1];
  const float* fs   = (const float*)d_in[2];
  // d_in[3] = mask (causal, regenerated in-kernel)
  const float* wq   = (const float*)d_in[4];
  const float* wq_b = (const float*)d_in[5];
  const float* wk   = (const float*)d_in[6];
  const float* wk_b = (const float*)d_in[7];
  const float* wv   = (const float*)d_in[8];
  const float* wv_b = (const float*)d_in[9];
  const float* wo   = (const float*)d_in[10];
  const float* wo_b = (const float*)d_in[11];
  const float* qn   = (const float*)d_in[12];
  const float* kn   = (const float*)d_in[13];
  float* out = (float*)d_out;

  char* ws = (char*)d_ws;
  u16*  xb    = (u16*)(ws);                          //  8 MB  x bf16 [2048][2048]
  u16*  wqkvT = (u16*)(ws + (size_t)(8  << 20));     // 12 MB  [3072][2048] bf16
  u16*  woT   = (u16*)(ws + (size_t)(20 << 20));     //  8 MB  [2048][2048] bf16
  float* qkv  = (float*)(ws + (size_t)(28 << 20));   // 24 MB  [2048][3072] f32
  u16*  Qg    = (u16*)(ws + (size_t)(52 << 20));     //  8 MB  [32][2048][64]
  u16*  Kg    = (u16*)(ws + (size_t)(60 << 20));     //  2 MB  [8][2048][64]
  u16*  Vg    = (u16*)(ws + (size_t)(62 << 20));     //  2 MB  [8][2048][64]
  u16*  att   = (u16*)(ws + (size_t)(64 << 20));     //  8 MB  [2048][2048]

  conv_bf16<<<4096, 256, 0, stream>>>(x, xb, 1048576);
  transpose_conv<<<dim3(32, 32), 256, 0, stream>>>(wq, wqkvT, 2048, 2048);
  transpose_conv<<<dim3(8, 32),  256, 0, stream>>>(wk, wqkvT + (size_t)2048 * 2048, 2048, 512);
  transpose_conv<<<dim3(8, 32),  256, 0, stream>>>(wv, wqkvT + (size_t)2560 * 2048, 2048, 512);
  transpose_conv<<<dim3(32, 32), 256, 0, stream>>>(wo, woT, 2048, 2048);
  gemm_bt<<<16 * 24, 256, 0, stream>>>(xb, wqkvT, qkv, (const float*)nullptr, 2048, 3072, 2048);
  qkv_post<<<24576, 256, 0, stream>>>(qkv, wq_b, wk_b, wv_b, qn, kn, fc, fs, Qg, Kg, Vg);
  attn_kernel<<<1024, 256, 0, stream>>>(Qg, Kg, Vg, att);
  gemm_bt<<<16 * 16, 256, 0, stream>>>(att, woT, out, wo_b, 2048, 2048, 2048);
}

// Round 4
// 196.242 us; speedup vs baseline: 1.1745x; 1.1297x over previous
//
#include <hip/hip_runtime.h>
#include <cstdint>

typedef unsigned short u16;
typedef __attribute__((ext_vector_type(8))) short short8;   // 8 x bf16 fragment
typedef __attribute__((ext_vector_type(4))) float f32x4;

__device__ __forceinline__ u16 f2bf(float f) {
  union { float f; uint32_t u; } c; c.f = f;
  return (u16)((c.u + 0x7FFFu + ((c.u >> 16) & 1u)) >> 16);
}

// ---------- fp32 -> bf16 elementwise (4 per thread) ----------
__global__ __launch_bounds__(256) void conv_bf16(const float* __restrict__ in,
                                                 u16* __restrict__ out, int n4) {
  int i = blockIdx.x * 256 + threadIdx.x;
  if (i >= n4) return;
  float4 v = ((const float4*)in)[i];
  ((ushort4*)out)[i] = make_ushort4(f2bf(v.x), f2bf(v.y), f2bf(v.z), f2bf(v.w));
}

// ---------- transpose + convert: in [K][N] f32 -> out [N][K] bf16 ----------
__global__ __launch_bounds__(256) void transpose_conv(const float* __restrict__ in,
                                                      u16* __restrict__ out, int K, int N) {
  __shared__ float tile[64][65];
  int n0 = blockIdx.x * 64, k0 = blockIdx.y * 64;
  int t = threadIdx.x;
  int a = t & 63, b4 = t >> 6;
#pragma unroll
  for (int j = 0; j < 16; ++j) {
    int kk = j * 4 + b4;
    tile[kk][a] = in[(size_t)(k0 + kk) * N + n0 + a];
  }
  __syncthreads();
#pragma unroll
  for (int j = 0; j < 16; ++j) {
    int nn = j * 4 + b4;
    out[(size_t)(n0 + nn) * K + k0 + a] = f2bf(tile[a][nn]);
  }
}

// ---------- bf16 GEMM: C[M][N] (f32,+bias) = A[M][K] * Bt[N][K]^T ----------
// 128x128 tile, BK=32, 4 waves (2x2), 16x16x32 MFMA, global_load_lds staging.
__global__ __launch_bounds__(256, 2) void gemm_bt(const u16* __restrict__ A,
                                                  const u16* __restrict__ Bt,
                                                  float* __restrict__ C,
                                                  const float* __restrict__ bias,
                                                  int M, int N, int K) {
  __shared__ alignas(16) u16 As[128 * 32];
  __shared__ alignas(16) u16 Bs[128 * 32];
  int nb = N >> 7;
  int m0 = (blockIdx.x / nb) << 7;
  int n0 = (blockIdx.x % nb) << 7;
  int tid = threadIdx.x;
  int w = tid >> 6, lane = tid & 63;
  int wr = w >> 1, wc = w & 1;
  int fr = lane & 15, hi = lane >> 4, fk = hi * 8;
  f32x4 acc[4][4] = {};
  for (int kt = 0; kt < K; kt += 32) {
#pragma unroll
    for (int b = 0; b < 2; ++b) {
      int chunk = b * 256 + tid;
      int r = chunk >> 2, c = chunk & 3;
      const u16* ga = A + (size_t)(m0 + r) * K + kt + c * 8;
      const u16* gb = Bt + (size_t)(n0 + r) * K + kt + c * 8;
      u16* la = As + (size_t)(b * 256 + w * 64) * 8;   // wave-uniform base
      u16* lb = Bs + (size_t)(b * 256 + w * 64) * 8;
      __builtin_amdgcn_global_load_lds((const __attribute__((address_space(1))) void*)ga,
                                       (__attribute__((address_space(3))) void*)la, 16, 0, 0);
      __builtin_amdgcn_global_load_lds((const __attribute__((address_space(1))) void*)gb,
                                       (__attribute__((address_space(3))) void*)lb, 16, 0, 0);
    }
    __syncthreads();
    short8 af[4], bfr[4];
#pragma unroll
    for (int m = 0; m < 4; ++m) af[m] = *(const short8*)&As[(wr * 64 + m * 16 + fr) * 32 + fk];
#pragma unroll
    for (int n = 0; n < 4; ++n) bfr[n] = *(const short8*)&Bs[(wc * 64 + n * 16 + fr) * 32 + fk];
#pragma unroll
    for (int m = 0; m < 4; ++m)
#pragma unroll
      for (int n = 0; n < 4; ++n)
        acc[m][n] = __builtin_amdgcn_mfma_f32_16x16x32_bf16(af[m], bfr[n], acc[m][n], 0, 0, 0);
    __syncthreads();
  }
#pragma unroll
  for (int m = 0; m < 4; ++m) {
#pragma unroll
    for (int n = 0; n < 4; ++n) {
      int gcol = n0 + wc * 64 + n * 16 + fr;
      float bv = bias ? bias[gcol] : 0.0f;
#pragma unroll
      for (int r = 0; r < 4; ++r) {
        int grow = m0 + wr * 64 + m * 16 + hi * 4 + r;
        C[(size_t)grow * N + gcol] = acc[m][n][r] + bv;
      }
    }
  }
}

// ---------- QKV postprocess: bias + RMSNorm + RoPE + layout [head][t][64] bf16 ----------
// one wave per (t, head); heads 0..31 = Q, 32..39 = K, 40..47 = V
__global__ __launch_bounds__(256) void qkv_post(const float* __restrict__ qkv,
    const float* __restrict__ wq_b, const float* __restrict__ wk_b, const float* __restrict__ wv_b,
    const float* __restrict__ qn_w, const float* __restrict__ kn_w,
    const float* __restrict__ fc, const float* __restrict__ fs,
    u16* __restrict__ Qg, u16* __restrict__ Kg, u16* __restrict__ Vg) {
  int gid = blockIdx.x * 256 + threadIdx.x;
  int wave = gid >> 6, d = gid & 63;
  int t = wave / 48, hh = wave % 48;
  float v;
  if (hh < 32)       v = qkv[(size_t)t * 3072 + hh * 64 + d] + wq_b[hh * 64 + d];
  else if (hh < 40)  v = qkv[(size_t)t * 3072 + 2048 + (hh - 32) * 64 + d] + wk_b[(hh - 32) * 64 + d];
  else               v = qkv[(size_t)t * 3072 + 2560 + (hh - 40) * 64 + d] + wv_b[(hh - 40) * 64 + d];
  if (hh < 40) {
    float sq = v * v;
#pragma unroll
    for (int off = 32; off >= 1; off >>= 1) sq += __shfl_xor(sq, off);
    float rr = rsqrtf(sq * (1.0f / 64.0f) + 1e-5f);
    float wn = (hh < 32) ? qn_w[d] : kn_w[d];
    v = v * rr * wn;
    float part = __shfl_xor(v, 1);
    float c = fc[t * 32 + (d >> 1)];
    float s = fs[t * 32 + (d >> 1)];
    v = (d & 1) ? (part * s + v * c) : (v * c - part * s);
  }
  u16 bv = f2bf(v);
  if (hh < 32)       Qg[((size_t)hh * 2048 + t) * 64 + d] = bv;
  else if (hh < 40)  Kg[((size_t)(hh - 32) * 2048 + t) * 64 + d] = bv;
  else               Vg[((size_t)(hh - 40) * 2048 + t) * 64 + d] = bv;
}

// ---------- causal GQA flash attention (v3: swapped QK^T, lane-local softmax) ----------
// grid 1024; balanced qt remap; XOR-swizzled K/V LDS; reg dbuf staging; defer-max.
__global__ __launch_bounds__(256, 2) void attn_kernel(const u16* __restrict__ Qg,
                                                      const u16* __restrict__ Kg,
                                                      const u16* __restrict__ Vg,
                                                      u16* __restrict__ att) {
  __shared__ alignas(16) u16 Ks[64 * 64];            // [key][d], XOR-swizzled rows
  __shared__ alignas(16) u16 Vs[64 * 64];            // [d][key], XOR-swizzled rows
  __shared__ alignas(16) uint32_t Ps[4][16 * 36];    // per-wave P: [q=fr][key-pair], stride 36
  char* KsB = (char*)Ks;
  char* VsB = (char*)Vs;

  // balanced remap: each CU's round-robin set {q0,15-q0,16+q0,31-q0} sums uniform
  int bid = blockIdx.x;
  int grp = bid >> 8, idx = bid & 255;
  int q0 = idx >> 5, h = idx & 31;
  int qt = (grp == 0) ? q0 : (grp == 1) ? 15 - q0 : (grp == 2) ? 16 + q0 : 31 - q0;
  int kvh = h >> 2;

  int tid = threadIdx.x, w = tid >> 6, lane = tid & 63;
  int fr = lane & 15, hi = lane >> 4, fk = hi * 8;
  const u16* qbase = Qg + ((size_t)h * 2048 + qt * 64 + w * 16 + fr) * 64;
  short8 qf0 = *(const short8*)(qbase + fk);
  short8 qf1 = *(const short8*)(qbase + 32 + fk);
  f32x4 o[4] = {};
  float mrow = -1e30f, lrow = 0.0f;   // per-lane stats for q-row (w*16+fr)

  // staging thread mapping
  int key0 = tid >> 3, c0 = tid & 7;                 // K: keys 0..31 (+32 second chunk)
  int kp = tid & 31, dg = tid >> 5, d0v = dg * 8;    // V: key pair 2kp,2kp+1, d rows d0v..d0v+7
  const u16* Kbase = Kg + (size_t)kvh * 2048 * 64;
  const u16* Vbase = Vg + (size_t)kvh * 2048 * 64;

  auto stage_load = [&](int kt2, short8& k0, short8& k1, short8& v0, short8& v1) {
    const u16* kb = Kbase + (size_t)kt2 * 64 * 64;
    k0 = *(const short8*)(kb + key0 * 64 + c0 * 8);
    k1 = *(const short8*)(kb + (32 + key0) * 64 + c0 * 8);
    const u16* vb = Vbase + (size_t)kt2 * 64 * 64 + (size_t)(2 * kp) * 64 + d0v;
    v0 = *(const short8*)vb;
    v1 = *(const short8*)(vb + 64);
  };
  auto stage_write = [&](short8 k0, short8 k1, short8 v0, short8 v1) {
    int offA = (key0 * 128 + c0 * 16) ^ ((key0 & 7) << 4);
    int offB = ((32 + key0) * 128 + c0 * 16) ^ ((key0 & 7) << 4);
    *(short8*)(KsB + offA) = k0;
    *(short8*)(KsB + offB) = k1;
#pragma unroll
    for (int j = 0; j < 8; ++j) {
      uint32_t pk = (uint32_t)(u16)v0[j] | ((uint32_t)(u16)v1[j] << 16);
      int d = d0v + j;
      int off = (d * 128 + kp * 4) ^ ((j & 7) << 4);   // d&7 == j
      *(uint32_t*)(VsB + off) = pk;
    }
  };

  short8 kA0, kA1, vA0, vA1, kB0, kB1, vB0, vB1;
  stage_load(0, kA0, kA1, vA0, vA1);

  uint32_t* Pw = &Ps[w][0];
  int swzr = (fr & 7) << 4;   // row-XOR for fragment reads
  int qrow = qt * 64 + w * 16 + fr;

  for (int kt = 0; kt <= qt; ++kt) {
    if ((kt & 1) == 0) stage_write(kA0, kA1, vA0, vA1);
    else               stage_write(kB0, kB1, vB0, vB1);
    __syncthreads();
    if (kt < qt) {   // prefetch next tile; lands under compute
      if ((kt & 1) == 0) stage_load(kt + 1, kB0, kB1, vB0, vB1);
      else               stage_load(kt + 1, kA0, kA1, vA0, vA1);
    }
    // S^T = K Q^T : lane (fr,hi) holds S[key=kt*64+g*16+hi*4+r][q-row=w*16+fr]
    f32x4 s4[4] = {};
    __builtin_amdgcn_s_setprio(1);
#pragma unroll
    for (int g = 0; g < 4; ++g) {
      int rb = (g * 16 + fr) * 128;
      short8 b0 = *(const short8*)(KsB + ((rb + hi * 16) ^ swzr));
      short8 b1 = *(const short8*)(KsB + ((rb + 64 + hi * 16) ^ swzr));
      s4[g] = __builtin_amdgcn_mfma_f32_16x16x32_bf16(b0, qf0, s4[g], 0, 0, 0);
      s4[g] = __builtin_amdgcn_mfma_f32_16x16x32_bf16(b1, qf1, s4[g], 0, 0, 0);
    }
    __builtin_amdgcn_s_setprio(0);
    // mask + scale in place; row max via 2 shfl
    int kbase = kt * 64 + hi * 4;
    float tmax = -1e30f;
#pragma unroll
    for (int g = 0; g < 4; ++g)
#pragma unroll
      for (int r = 0; r < 4; ++r) {
        float x = s4[g][r] * 0.125f;
        x = (kbase + g * 16 + r > qrow) ? -1e30f : x;
        s4[g][r] = x;
        tmax = fmaxf(tmax, x);
      }
    tmax = fmaxf(tmax, __shfl_xor(tmax, 16));
    tmax = fmaxf(tmax, __shfl_xor(tmax, 32));
    // defer-max: skip rescale when tile max doesn't push the running max by >8
    if (!__all((tmax - mrow) <= 8.0f)) {
      float mn = fmaxf(mrow, tmax);
      float alpha = __expf(mrow - mn);
      mrow = mn;
#pragma unroll
      for (int r = 0; r < 4; ++r) {
        float ar = __shfl(alpha, hi * 4 + r);
#pragma unroll
        for (int g2 = 0; g2 < 4; ++g2) o[g2][r] *= ar;
      }
      lrow *= alpha;
    }
    // P = exp(S - m), lane-parallel; pack to bf16 pairs; row sum via 2 shfl
    float rsum = 0.0f;
#pragma unroll
    for (int g = 0; g < 4; ++g) {
      float p0 = __expf(s4[g][0] - mrow);
      float p1 = __expf(s4[g][1] - mrow);
      float p2 = __expf(s4[g][2] - mrow);
      float p3 = __expf(s4[g][3] - mrow);
      rsum += (p0 + p1) + (p2 + p3);
      uint2 pk = make_uint2((uint32_t)f2bf(p0) | ((uint32_t)f2bf(p1) << 16),
                            (uint32_t)f2bf(p2) | ((uint32_t)f2bf(p3) << 16));
      *(uint2*)&Pw[fr * 36 + g * 8 + hi * 2] = pk;   // conflict-free b64
    }
    rsum += __shfl_xor(rsum, 16);
    rsum += __shfl_xor(rsum, 32);
    lrow += rsum;
    asm volatile("s_waitcnt lgkmcnt(0)" ::: "memory");  // P writes land (wave-local)
    // O += P V  (A-operand read back: stride 36 u32 -> slot stride 9 == conflict-free)
    short8 pa0 = *(const short8*)&Pw[fr * 36 + hi * 4];
    short8 pa1 = *(const short8*)&Pw[fr * 36 + 16 + hi * 4];
    __builtin_amdgcn_s_setprio(1);
#pragma unroll
    for (int g2 = 0; g2 < 4; ++g2) {
      int rb = (g2 * 16 + fr) * 128;
      short8 vb0 = *(const short8*)(VsB + ((rb + hi * 16) ^ swzr));
      short8 vb1 = *(const short8*)(VsB + ((rb + 64 + hi * 16) ^ swzr));
      o[g2] = __builtin_amdgcn_mfma_f32_16x16x32_bf16(pa0, vb0, o[g2], 0, 0, 0);
      o[g2] = __builtin_amdgcn_mfma_f32_16x16x32_bf16(pa1, vb1, o[g2], 0, 0, 0);
    }
    __builtin_amdgcn_s_setprio(0);
    __syncthreads();
  }
#pragma unroll
  for (int r = 0; r < 4; ++r) {
    float li = __shfl(lrow, hi * 4 + r);
    float inv = 1.0f / li;
    size_t rowoff = (size_t)(qt * 64 + w * 16 + hi * 4 + r) * 2048 + h * 64;
#pragma unroll
    for (int g2 = 0; g2 < 4; ++g2)
      att[rowoff + g2 * 16 + fr] = f2bf(o[g2][r] * inv);
  }
}

extern "C" void kernel_launch(void* const* d_in, const int* in_sizes, int n_in,
                              void* d_out, int out_size, void* d_ws, size_t ws_size,
                              hipStream_t stream) {
  const float* x    = (const float*)d_in[0];
  const float* fc   = (const float*)d_in[1];
  const float* fs   = (const float*)d_in[2];
  // d_in[3] = mask (causal, regenerated in-kernel)
  const float* wq   = (const float*)d_in[4];
  const float* wq_b = (const float*)d_in[5];
  const float* wk   = (const float*)d_in[6];
  const float* wk_b = (const float*)d_in[7];
  const float* wv   = (const float*)d_in[8];
  const float* wv_b = (const float*)d_in[9];
  const float* wo   = (const float*)d_in[10];
  const float* wo_b = (const float*)d_in[11];
  const float* qn   = (const float*)d_in[12];
  const float* kn   = (const float*)d_in[13];
  float* out = (float*)d_out;

  char* ws = (char*)d_ws;
  u16*  xb    = (u16*)(ws);                          //  8 MB  x bf16 [2048][2048]
  u16*  wqkvT = (u16*)(ws + (size_t)(8  << 20));     // 12 MB  [3072][2048] bf16
  u16*  woT   = (u16*)(ws + (size_t)(20 << 20));     //  8 MB  [2048][2048] bf16
  float* qkv  = (float*)(ws + (size_t)(28 << 20));   // 24 MB  [2048][3072] f32
  u16*  Qg    = (u16*)(ws + (size_t)(52 << 20));     //  8 MB  [32][2048][64]
  u16*  Kg    = (u16*)(ws + (size_t)(60 << 20));     //  2 MB  [8][2048][64]
  u16*  Vg    = (u16*)(ws + (size_t)(62 << 20));     //  2 MB  [8][2048][64]
  u16*  att   = (u16*)(ws + (size_t)(64 << 20));     //  8 MB  [2048][2048]

  conv_bf16<<<4096, 256, 0, stream>>>(x, xb, 1048576);
  transpose_conv<<<dim3(32, 32), 256, 0, stream>>>(wq, wqkvT, 2048, 2048);
  transpose_conv<<<dim3(8, 32),  256, 0, stream>>>(wk, wqkvT + (size_t)2048 * 2048, 2048, 512);
  transpose_conv<<<dim3(8, 32),  256, 0, stream>>>(wv, wqkvT + (size_t)2560 * 2048, 2048, 512);
  transpose_conv<<<dim3(32, 32), 256, 0, stream>>>(wo, woT, 2048, 2048);
  gemm_bt<<<16 * 24, 256, 0, stream>>>(xb, wqkvT, qkv, (const float*)nullptr, 2048, 3072, 2048);
  qkv_post<<<24576, 256, 0, stream>>>(qkv, wq_b, wk_b, wv_b, qn, kn, fc, fs, Qg, Kg, Vg);
  attn_kernel<<<1024, 256, 0, stream>>>(Qg, Kg, Vg, att);
  gemm_bt<<<16 * 16, 256, 0, stream>>>(att, woT, out, wo_b, 2048, 2048, 2048);
}

// Round 7
// 191.875 us; speedup vs baseline: 1.2013x; 1.0228x over previous
//
#include <hip/hip_runtime.h>
#include <hip/hip_bf16.h>
#include <cstdint>

typedef unsigned short u16;
typedef __attribute__((ext_vector_type(8))) short short8;   // 8 x bf16 fragment
typedef __attribute__((ext_vector_type(4))) float f32x4;

__device__ __forceinline__ u16 f2bf(float f) {
  union { float f; uint32_t u; } c; c.f = f;
  return (u16)((c.u + 0x7FFFu + ((c.u >> 16) & 1u)) >> 16);
}

__device__ __forceinline__ uint32_t pack_bf16x2(float a, float b) {
  union { __hip_bfloat162 h; uint32_t u; } c;
  c.h = __float22bfloat162_rn(make_float2(a, b));   // v_cvt_pk_bf16_f32
  return c.u;
}

// ---------- fp32 -> bf16 elementwise (4 per thread) ----------
__global__ __launch_bounds__(256) void conv_bf16(const float* __restrict__ in,
                                                 u16* __restrict__ out, int n4) {
  int i = blockIdx.x * 256 + threadIdx.x;
  if (i >= n4) return;
  float4 v = ((const float4*)in)[i];
  ((ushort4*)out)[i] = make_ushort4(f2bf(v.x), f2bf(v.y), f2bf(v.z), f2bf(v.w));
}

// ---------- transpose + convert: in [K][N] f32 -> out [N][K] bf16 ----------
__global__ __launch_bounds__(256) void transpose_conv(const float* __restrict__ in,
                                                      u16* __restrict__ out, int K, int N) {
  __shared__ float tile[64][65];
  int n0 = blockIdx.x * 64, k0 = blockIdx.y * 64;
  int t = threadIdx.x;
  int a = t & 63, b4 = t >> 6;
#pragma unroll
  for (int j = 0; j < 16; ++j) {
    int kk = j * 4 + b4;
    tile[kk][a] = in[(size_t)(k0 + kk) * N + n0 + a];
  }
  __syncthreads();
#pragma unroll
  for (int j = 0; j < 16; ++j) {
    int nn = j * 4 + b4;
    out[(size_t)(n0 + nn) * K + k0 + a] = f2bf(tile[a][nn]);
  }
}

// ---------- bf16 GEMM: C[M][N] (f32,+bias) = A[M][K] * Bt[N][K]^T ----------
// 128x128 tile, BK=32, 4 waves (2x2), 16x16x32 MFMA, global_load_lds staging.
__global__ __launch_bounds__(256, 2) void gemm_bt(const u16* __restrict__ A,
                                                  const u16* __restrict__ Bt,
                                                  float* __restrict__ C,
                                                  const float* __restrict__ bias,
                                                  int M, int N, int K) {
  __shared__ alignas(16) u16 As[128 * 32];
  __shared__ alignas(16) u16 Bs[128 * 32];
  int nb = N >> 7;
  int m0 = (blockIdx.x / nb) << 7;
  int n0 = (blockIdx.x % nb) << 7;
  int tid = threadIdx.x;
  int w = tid >> 6, lane = tid & 63;
  int wr = w >> 1, wc = w & 1;
  int fr = lane & 15, hi = lane >> 4, fk = hi * 8;
  f32x4 acc[4][4] = {};
  for (int kt = 0; kt < K; kt += 32) {
#pragma unroll
    for (int b = 0; b < 2; ++b) {
      int chunk = b * 256 + tid;
      int r = chunk >> 2, c = chunk & 3;
      const u16* ga = A + (size_t)(m0 + r) * K + kt + c * 8;
      const u16* gb = Bt + (size_t)(n0 + r) * K + kt + c * 8;
      u16* la = As + (size_t)(b * 256 + w * 64) * 8;   // wave-uniform base
      u16* lb = Bs + (size_t)(b * 256 + w * 64) * 8;
      __builtin_amdgcn_global_load_lds((const __attribute__((address_space(1))) void*)ga,
                                       (__attribute__((address_space(3))) void*)la, 16, 0, 0);
      __builtin_amdgcn_global_load_lds((const __attribute__((address_space(1))) void*)gb,
                                       (__attribute__((address_space(3))) void*)lb, 16, 0, 0);
    }
    __syncthreads();
    short8 af[4], bfr[4];
#pragma unroll
    for (int m = 0; m < 4; ++m) af[m] = *(const short8*)&As[(wr * 64 + m * 16 + fr) * 32 + fk];
#pragma unroll
    for (int n = 0; n < 4; ++n) bfr[n] = *(const short8*)&Bs[(wc * 64 + n * 16 + fr) * 32 + fk];
#pragma unroll
    for (int m = 0; m < 4; ++m)
#pragma unroll
      for (int n = 0; n < 4; ++n)
        acc[m][n] = __builtin_amdgcn_mfma_f32_16x16x32_bf16(af[m], bfr[n], acc[m][n], 0, 0, 0);
    __syncthreads();
  }
#pragma unroll
  for (int m = 0; m < 4; ++m) {
#pragma unroll
    for (int n = 0; n < 4; ++n) {
      int gcol = n0 + wc * 64 + n * 16 + fr;
      float bv = bias ? bias[gcol] : 0.0f;
#pragma unroll
      for (int r = 0; r < 4; ++r) {
        int grow = m0 + wr * 64 + m * 16 + hi * 4 + r;
        C[(size_t)grow * N + gcol] = acc[m][n][r] + bv;
      }
    }
  }
}

// ---------- QKV postprocess: bias + RMSNorm + RoPE + layout [head][t][64] bf16 ----------
// one wave per (t, head); heads 0..31 = Q (pre-scaled by 0.125*log2e), 32..39 = K, 40..47 = V
__global__ __launch_bounds__(256) void qkv_post(const float* __restrict__ qkv,
    const float* __restrict__ wq_b, const float* __restrict__ wk_b, const float* __restrict__ wv_b,
    const float* __restrict__ qn_w, const float* __restrict__ kn_w,
    const float* __restrict__ fc, const float* __restrict__ fs,
    u16* __restrict__ Qg, u16* __restrict__ Kg, u16* __restrict__ Vg) {
  int gid = blockIdx.x * 256 + threadIdx.x;
  int wave = gid >> 6, d = gid & 63;
  int t = wave / 48, hh = wave % 48;
  float v;
  if (hh < 32)       v = qkv[(size_t)t * 3072 + hh * 64 + d] + wq_b[hh * 64 + d];
  else if (hh < 40)  v = qkv[(size_t)t * 3072 + 2048 + (hh - 32) * 64 + d] + wk_b[(hh - 32) * 64 + d];
  else               v = qkv[(size_t)t * 3072 + 2560 + (hh - 40) * 64 + d] + wv_b[(hh - 40) * 64 + d];
  if (hh < 40) {
    float sq = v * v;
#pragma unroll
    for (int off = 32; off >= 1; off >>= 1) sq += __shfl_xor(sq, off);
    float rr = rsqrtf(sq * (1.0f / 64.0f) + 1e-5f);
    float wn = (hh < 32) ? qn_w[d] * 0.18033688f : kn_w[d];   // Q: fold 0.125*log2(e)
    v = v * rr * wn;
    float part = __shfl_xor(v, 1);
    float c = fc[t * 32 + (d >> 1)];
    float s = fs[t * 32 + (d >> 1)];
    v = (d & 1) ? (part * s + v * c) : (v * c - part * s);
  }
  u16 bv = f2bf(v);
  if (hh < 32)       Qg[((size_t)hh * 2048 + t) * 64 + d] = bv;
  else if (hh < 40)  Kg[((size_t)(hh - 32) * 2048 + t) * 64 + d] = bv;
  else               Vg[((size_t)(hh - 40) * 2048 + t) * 64 + d] = bv;
}

// ---------- causal GQA flash attention (v4: log2-domain softmax, diag-only mask) ----------
__global__ __launch_bounds__(256, 2) void attn_kernel(const u16* __restrict__ Qg,
                                                      const u16* __restrict__ Kg,
                                                      const u16* __restrict__ Vg,
                                                      u16* __restrict__ att) {
  __shared__ alignas(16) u16 Ks[64 * 64];            // [key][d], XOR-swizzled rows
  __shared__ alignas(16) u16 Vs[64 * 64];            // [d][key], XOR-swizzled rows
  __shared__ alignas(16) uint32_t Ps[4][16 * 36];    // per-wave P: [q=fr][key-pair], stride 36
  char* KsB = (char*)Ks;
  char* VsB = (char*)Vs;

  // balanced remap: each CU's round-robin set {q0,15-q0,16+q0,31-q0} sums uniform
  int bid = blockIdx.x;
  int grp = bid >> 8, idx = bid & 255;
  int q0 = idx >> 5, h = idx & 31;
  int qt = (grp == 0) ? q0 : (grp == 1) ? 15 - q0 : (grp == 2) ? 16 + q0 : 31 - q0;
  int kvh = h >> 2;

  int tid = threadIdx.x, w = tid >> 6, lane = tid & 63;
  int fr = lane & 15, hi = lane >> 4, fk = hi * 8;
  const u16* qbase = Qg + ((size_t)h * 2048 + qt * 64 + w * 16 + fr) * 64;
  short8 qf0 = *(const short8*)(qbase + fk);
  short8 qf1 = *(const short8*)(qbase + 32 + fk);
  f32x4 o[4] = {};
  float mrow = -1e30f, lrow = 0.0f;   // per-lane stats for q-row (w*16+fr), log2 domain

  // staging thread mapping
  int key0 = tid >> 3, c0 = tid & 7;                 // K: keys 0..31 (+32 second chunk)
  int kp = tid & 31, dg = tid >> 5, d0v = dg * 8;    // V: key pair 2kp,2kp+1, d rows d0v..d0v+7
  const u16* Kbase = Kg + (size_t)kvh * 2048 * 64;
  const u16* Vbase = Vg + (size_t)kvh * 2048 * 64;

  auto stage_load = [&](int kt2, short8& k0, short8& k1, short8& v0, short8& v1) {
    const u16* kb = Kbase + (size_t)kt2 * 64 * 64;
    k0 = *(const short8*)(kb + key0 * 64 + c0 * 8);
    k1 = *(const short8*)(kb + (32 + key0) * 64 + c0 * 8);
    const u16* vb = Vbase + (size_t)kt2 * 64 * 64 + (size_t)(2 * kp) * 64 + d0v;
    v0 = *(const short8*)vb;
    v1 = *(const short8*)(vb + 64);
  };
  auto stage_write = [&](short8 k0, short8 k1, short8 v0, short8 v1) {
    int offA = (key0 * 128 + c0 * 16) ^ ((key0 & 7) << 4);
    int offB = ((32 + key0) * 128 + c0 * 16) ^ ((key0 & 7) << 4);
    *(short8*)(KsB + offA) = k0;
    *(short8*)(KsB + offB) = k1;
#pragma unroll
    for (int j = 0; j < 8; ++j) {
      uint32_t pk = (uint32_t)(u16)v0[j] | ((uint32_t)(u16)v1[j] << 16);
      int d = d0v + j;
      int off = (d * 128 + kp * 4) ^ ((j & 7) << 4);   // d&7 == j
      *(uint32_t*)(VsB + off) = pk;
    }
  };

  short8 kA0, kA1, vA0, vA1, kB0, kB1, vB0, vB1;
  stage_load(0, kA0, kA1, vA0, vA1);

  uint32_t* Pw = &Ps[w][0];
  int swzr = (fr & 7) << 4;   // row-XOR for fragment reads
  int qrow = qt * 64 + w * 16 + fr;

  for (int kt = 0; kt <= qt; ++kt) {
    bool diag = (kt == qt);
    if ((kt & 1) == 0) stage_write(kA0, kA1, vA0, vA1);
    else               stage_write(kB0, kB1, vB0, vB1);
    __syncthreads();
    if (!diag) {   // prefetch next tile; lands under compute
      if ((kt & 1) == 0) stage_load(kt + 1, kB0, kB1, vB0, vB1);
      else               stage_load(kt + 1, kA0, kA1, vA0, vA1);
    }
    // S^T = K Q^T : lane (fr,hi) holds S[key=kt*64+g*16+hi*4+r][q-row=w*16+fr], log2 units
    f32x4 s4[4] = {};
    __builtin_amdgcn_s_setprio(1);
#pragma unroll
    for (int g = 0; g < 4; ++g) {
      int rb = (g * 16 + fr) * 128;
      short8 b0 = *(const short8*)(KsB + ((rb + hi * 16) ^ swzr));
      short8 b1 = *(const short8*)(KsB + ((rb + 64 + hi * 16) ^ swzr));
      s4[g] = __builtin_amdgcn_mfma_f32_16x16x32_bf16(b0, qf0, s4[g], 0, 0, 0);
      s4[g] = __builtin_amdgcn_mfma_f32_16x16x32_bf16(b1, qf1, s4[g], 0, 0, 0);
    }
    __builtin_amdgcn_s_setprio(0);
    // causal mask: only the diagonal tile crosses q==k
    if (diag) {
      int kbase = kt * 64 + hi * 4;
#pragma unroll
      for (int g = 0; g < 4; ++g)
#pragma unroll
        for (int r = 0; r < 4; ++r)
          if (kbase + g * 16 + r > qrow) s4[g][r] = -1e30f;
    }
    float tmax = -1e30f;
#pragma unroll
    for (int g = 0; g < 4; ++g)
#pragma unroll
      for (int r = 0; r < 4; ++r) tmax = fmaxf(tmax, s4[g][r]);
    tmax = fmaxf(tmax, __shfl_xor(tmax, 16));
    tmax = fmaxf(tmax, __shfl_xor(tmax, 32));
    // defer-max (log2 domain: 8*log2e ~ 11.54)
    if (!__all((tmax - mrow) <= 11.54f)) {
      float mn = fmaxf(mrow, tmax);
      float alpha = exp2f(mrow - mn);
      mrow = mn;
#pragma unroll
      for (int r = 0; r < 4; ++r) {
        float ar = __shfl(alpha, hi * 4 + r);
#pragma unroll
        for (int g2 = 0; g2 < 4; ++g2) o[g2][r] *= ar;
      }
      lrow *= alpha;
    }
    // P = exp2(S - m), lane-parallel; cvt_pk pack; row sum via 2 shfl
    float rsum = 0.0f;
#pragma unroll
    for (int g = 0; g < 4; ++g) {
      float p0 = exp2f(s4[g][0] - mrow);
      float p1 = exp2f(s4[g][1] - mrow);
      float p2 = exp2f(s4[g][2] - mrow);
      float p3 = exp2f(s4[g][3] - mrow);
      rsum += (p0 + p1) + (p2 + p3);
      uint2 pk = make_uint2(pack_bf16x2(p0, p1), pack_bf16x2(p2, p3));
      *(uint2*)&Pw[fr * 36 + g * 8 + hi * 2] = pk;   // b64
    }
    rsum += __shfl_xor(rsum, 16);
    rsum += __shfl_xor(rsum, 32);
    lrow += rsum;
    asm volatile("s_waitcnt lgkmcnt(0)" ::: "memory");  // P writes land (wave-local)
    // O += P V  (A-operand read back: u32 stride 36 -> b128 slot stride 9, conflict-free)
    short8 pa0 = *(const short8*)&Pw[fr * 36 + hi * 4];
    short8 pa1 = *(const short8*)&Pw[fr * 36 + 16 + hi * 4];
    __builtin_amdgcn_s_setprio(1);
#pragma unroll
    for (int g2 = 0; g2 < 4; ++g2) {
      int rb = (g2 * 16 + fr) * 128;
      short8 vb0 = *(const short8*)(VsB + ((rb + hi * 16) ^ swzr));
      short8 vb1 = *(const short8*)(VsB + ((rb + 64 + hi * 16) ^ swzr));
      o[g2] = __builtin_amdgcn_mfma_f32_16x16x32_bf16(pa0, vb0, o[g2], 0, 0, 0);
      o[g2] = __builtin_amdgcn_mfma_f32_16x16x32_bf16(pa1, vb1, o[g2], 0, 0, 0);
    }
    __builtin_amdgcn_s_setprio(0);
    __syncthreads();
  }
#pragma unroll
  for (int r = 0; r < 4; ++r) {
    float li = __shfl(lrow, hi * 4 + r);
    float inv = 1.0f / li;
    size_t rowoff = (size_t)(qt * 64 + w * 16 + hi * 4 + r) * 2048 + h * 64;
#pragma unroll
    for (int g2 = 0; g2 < 4; ++g2)
      att[rowoff + g2 * 16 + fr] = f2bf(o[g2][r] * inv);
  }
}

extern "C" void kernel_launch(void* const* d_in, const int* in_sizes, int n_in,
                              void* d_out, int out_size, void* d_ws, size_t ws_size,
                              hipStream_t stream) {
  const float* x    = (const float*)d_in[0];
  const float* fc   = (const float*)d_in[1];
  const float* fs   = (const float*)d_in[2];
  // d_in[3] = mask (causal, regenerated in-kernel)
  const float* wq   = (const float*)d_in[4];
  const float* wq_b = (const float*)d_in[5];
  const float* wk   = (const float*)d_in[6];
  const float* wk_b = (const float*)d_in[7];
  const float* wv   = (const float*)d_in[8];
  const float* wv_b = (const float*)d_in[9];
  const float* wo   = (const float*)d_in[10];
  const float* wo_b = (const float*)d_in[11];
  const float* qn   = (const float*)d_in[12];
  const float* kn   = (const float*)d_in[13];
  float* out = (float*)d_out;

  char* ws = (char*)d_ws;
  u16*  xb    = (u16*)(ws);                          //  8 MB  x bf16 [2048][2048]
  u16*  wqkvT = (u16*)(ws + (size_t)(8  << 20));     // 12 MB  [3072][2048] bf16
  u16*  woT   = (u16*)(ws + (size_t)(20 << 20));     //  8 MB  [2048][2048] bf16
  float* qkv  = (float*)(ws + (size_t)(28 << 20));   // 24 MB  [2048][3072] f32
  u16*  Qg    = (u16*)(ws + (size_t)(52 << 20));     //  8 MB  [32][2048][64]
  u16*  Kg    = (u16*)(ws + (size_t)(60 << 20));     //  2 MB  [8][2048][64]
  u16*  Vg    = (u16*)(ws + (size_t)(62 << 20));     //  2 MB  [8][2048][64]
  u16*  att   = (u16*)(ws + (size_t)(64 << 20));     //  8 MB  [2048][2048]

  conv_bf16<<<4096, 256, 0, stream>>>(x, xb, 1048576);
  transpose_conv<<<dim3(32, 32), 256, 0, stream>>>(wq, wqkvT, 2048, 2048);
  transpose_conv<<<dim3(8, 32),  256, 0, stream>>>(wk, wqkvT + (size_t)2048 * 2048, 2048, 512);
  transpose_conv<<<dim3(8, 32),  256, 0, stream>>>(wv, wqkvT + (size_t)2560 * 2048, 2048, 512);
  transpose_conv<<<dim3(32, 32), 256, 0, stream>>>(wo, woT, 2048, 2048);
  gemm_bt<<<16 * 24, 256, 0, stream>>>(xb, wqkvT, qkv, (const float*)nullptr, 2048, 3072, 2048);
  qkv_post<<<24576, 256, 0, stream>>>(qkv, wq_b, wk_b, wv_b, qn, kn, fc, fs, Qg, Kg, Vg);
  attn_kernel<<<1024, 256, 0, stream>>>(Qg, Kg, Vg, att);
  gemm_bt<<<16 * 16, 256, 0, stream>>>(att, woT, out, wo_b, 2048, 2048, 2048);
}

// Round 8
// 190.448 us; speedup vs baseline: 1.2103x; 1.0075x over previous
//
#include <hip/hip_runtime.h>
#include <hip/hip_bf16.h>
#include <cstdint>

typedef unsigned short u16;
typedef __attribute__((ext_vector_type(8))) short short8;   // 8 x bf16 fragment
typedef __attribute__((ext_vector_type(4))) float f32x4;

__device__ __forceinline__ u16 f2bf(float f) {
  union { float f; uint32_t u; } c; c.f = f;
  return (u16)((c.u + 0x7FFFu + ((c.u >> 16) & 1u)) >> 16);
}

__device__ __forceinline__ uint32_t pack_bf16x2(float a, float b) {
  union { __hip_bfloat162 h; uint32_t u; } c;
  c.h = __float22bfloat162_rn(make_float2(a, b));   // v_cvt_pk_bf16_f32
  return c.u;
}

// ---------- fp32 -> bf16 elementwise (4 per thread) ----------
__global__ __launch_bounds__(256) void conv_bf16(const float* __restrict__ in,
                                                 u16* __restrict__ out, int n4) {
  int i = blockIdx.x * 256 + threadIdx.x;
  if (i >= n4) return;
  float4 v = ((const float4*)in)[i];
  ((ushort4*)out)[i] = make_ushort4(f2bf(v.x), f2bf(v.y), f2bf(v.z), f2bf(v.w));
}

// ---------- transpose + convert: in [K][N] f32 -> out [N][K] bf16 ----------
__global__ __launch_bounds__(256) void transpose_conv(const float* __restrict__ in,
                                                      u16* __restrict__ out, int K, int N) {
  __shared__ float tile[64][65];
  int n0 = blockIdx.x * 64, k0 = blockIdx.y * 64;
  int t = threadIdx.x;
  int a = t & 63, b4 = t >> 6;
#pragma unroll
  for (int j = 0; j < 16; ++j) {
    int kk = j * 4 + b4;
    tile[kk][a] = in[(size_t)(k0 + kk) * N + n0 + a];
  }
  __syncthreads();
#pragma unroll
  for (int j = 0; j < 16; ++j) {
    int nn = j * 4 + b4;
    out[(size_t)(n0 + nn) * K + k0 + a] = f2bf(tile[a][nn]);
  }
}

// ---------- bf16 GEMM: C[M][N] (f32,+bias) = A[M][K] * Bt[N][K]^T ----------
// 128x128 tile, BK=32, 2-phase double-buffered LDS, XCD-swizzled grid.
__global__ __launch_bounds__(256, 3) void gemm_bt(const u16* __restrict__ A,
                                                  const u16* __restrict__ Bt,
                                                  float* __restrict__ C,
                                                  const float* __restrict__ bias,
                                                  int M, int N, int K) {
  __shared__ alignas(16) u16 As[2][128 * 32];
  __shared__ alignas(16) u16 Bs[2][128 * 32];
  int nb = N >> 7;
  // bijective XCD swizzle (grid % 8 == 0 for both call sites)
  int nwg = gridDim.x;
  int cpx = nwg >> 3;
  int bid = blockIdx.x;
  int swz = (bid & 7) * cpx + (bid >> 3);
  int m0 = (swz / nb) << 7;
  int n0 = (swz % nb) << 7;
  int tid = threadIdx.x;
  int w = tid >> 6, lane = tid & 63;
  int wr = w >> 1, wc = w & 1;
  int fr = lane & 15, hi = lane >> 4, fk = hi * 8;
  int r0 = tid >> 2, c0 = tid & 3;

  auto STAGE = [&](int buf, int kt) {
#pragma unroll
    for (int b = 0; b < 2; ++b) {
      int r = (b << 6) + r0;
      const u16* ga = A + (size_t)(m0 + r) * K + kt + c0 * 8;
      const u16* gb = Bt + (size_t)(n0 + r) * K + kt + c0 * 8;
      u16* la = &As[buf][(size_t)(b * 256 + w * 64) * 8];   // wave-uniform base
      u16* lb = &Bs[buf][(size_t)(b * 256 + w * 64) * 8];
      __builtin_amdgcn_global_load_lds((const __attribute__((address_space(1))) void*)ga,
                                       (__attribute__((address_space(3))) void*)la, 16, 0, 0);
      __builtin_amdgcn_global_load_lds((const __attribute__((address_space(1))) void*)gb,
                                       (__attribute__((address_space(3))) void*)lb, 16, 0, 0);
    }
  };

  f32x4 acc[4][4] = {};
  STAGE(0, 0);
  __syncthreads();
  int cur = 0;
  for (int kt = 0; kt < K; kt += 32) {
    if (kt + 32 < K) STAGE(cur ^ 1, kt + 32);   // overlap next-tile HBM with compute
    short8 af[4], bfr[4];
#pragma unroll
    for (int m = 0; m < 4; ++m) af[m] = *(const short8*)&As[cur][(wr * 64 + m * 16 + fr) * 32 + fk];
#pragma unroll
    for (int n = 0; n < 4; ++n) bfr[n] = *(const short8*)&Bs[cur][(wc * 64 + n * 16 + fr) * 32 + fk];
#pragma unroll
    for (int m = 0; m < 4; ++m)
#pragma unroll
      for (int n = 0; n < 4; ++n)
        acc[m][n] = __builtin_amdgcn_mfma_f32_16x16x32_bf16(af[m], bfr[n], acc[m][n], 0, 0, 0);
    __syncthreads();   // drains vmcnt(0)+lgkmcnt(0): staged tile ready, reads done
    cur ^= 1;
  }
#pragma unroll
  for (int m = 0; m < 4; ++m) {
#pragma unroll
    for (int n = 0; n < 4; ++n) {
      int gcol = n0 + wc * 64 + n * 16 + fr;
      float bv = bias ? bias[gcol] : 0.0f;
#pragma unroll
      for (int r = 0; r < 4; ++r) {
        int grow = m0 + wr * 64 + m * 16 + hi * 4 + r;
        C[(size_t)grow * N + gcol] = acc[m][n][r] + bv;
      }
    }
  }
}

// ---------- QKV postprocess: bias + RMSNorm + RoPE + layout [head][t][64] bf16 ----------
// one wave per (t, head); heads 0..31 = Q (pre-scaled by 0.125*log2e), 32..39 = K, 40..47 = V
__global__ __launch_bounds__(256) void qkv_post(const float* __restrict__ qkv,
    const float* __restrict__ wq_b, const float* __restrict__ wk_b, const float* __restrict__ wv_b,
    const float* __restrict__ qn_w, const float* __restrict__ kn_w,
    const float* __restrict__ fc, const float* __restrict__ fs,
    u16* __restrict__ Qg, u16* __restrict__ Kg, u16* __restrict__ Vg) {
  int gid = blockIdx.x * 256 + threadIdx.x;
  int wave = gid >> 6, d = gid & 63;
  int t = wave / 48, hh = wave % 48;
  float v;
  if (hh < 32)       v = qkv[(size_t)t * 3072 + hh * 64 + d] + wq_b[hh * 64 + d];
  else if (hh < 40)  v = qkv[(size_t)t * 3072 + 2048 + (hh - 32) * 64 + d] + wk_b[(hh - 32) * 64 + d];
  else               v = qkv[(size_t)t * 3072 + 2560 + (hh - 40) * 64 + d] + wv_b[(hh - 40) * 64 + d];
  if (hh < 40) {
    float sq = v * v;
#pragma unroll
    for (int off = 32; off >= 1; off >>= 1) sq += __shfl_xor(sq, off);
    float rr = rsqrtf(sq * (1.0f / 64.0f) + 1e-5f);
    float wn = (hh < 32) ? qn_w[d] * 0.18033688f : kn_w[d];   // Q: fold 0.125*log2(e)
    v = v * rr * wn;
    float part = __shfl_xor(v, 1);
    float c = fc[t * 32 + (d >> 1)];
    float s = fs[t * 32 + (d >> 1)];
    v = (d & 1) ? (part * s + v * c) : (v * c - part * s);
  }
  u16 bv = f2bf(v);
  if (hh < 32)       Qg[((size_t)hh * 2048 + t) * 64 + d] = bv;
  else if (hh < 40)  Kg[((size_t)(hh - 32) * 2048 + t) * 64 + d] = bv;
  else               Vg[((size_t)(hh - 40) * 2048 + t) * 64 + d] = bv;
}

// ---------- softmax upper bound: S_log2 <= 11.5416 * max|qn| * max|kn| ----------
__global__ void bound_kernel(const float* __restrict__ qn, const float* __restrict__ kn,
                             float* __restrict__ out) {
  int d = threadIdx.x;   // 64 threads
  float a = fabsf(qn[d]), b = fabsf(kn[d]);
#pragma unroll
  for (int off = 32; off >= 1; off >>= 1) {
    a = fmaxf(a, __shfl_xor(a, off));
    b = fmaxf(b, __shfl_xor(b, off));
  }
  if (d == 0) out[0] = 11.5416222f * a * b;
}

// ---------- causal GQA flash attention (v5: fixed-max, no in-loop reductions) ----------
__global__ __launch_bounds__(256, 2) void attn_kernel(const u16* __restrict__ Qg,
                                                      const u16* __restrict__ Kg,
                                                      const u16* __restrict__ Vg,
                                                      const float* __restrict__ bound,
                                                      u16* __restrict__ att) {
  __shared__ alignas(16) u16 Ks[64 * 64];            // [key][d], XOR-swizzled rows
  __shared__ alignas(16) u16 Vs[64 * 64];            // [d][key], XOR-swizzled rows
  __shared__ alignas(16) uint32_t Ps[4][16 * 36];    // per-wave P: [q=fr][key-pair], stride 36
  char* KsB = (char*)Ks;
  char* VsB = (char*)Vs;

  // balanced remap: each CU's round-robin set {q0,15-q0,16+q0,31-q0} sums uniform
  int bid = blockIdx.x;
  int grp = bid >> 8, idx = bid & 255;
  int q0 = idx >> 5, h = idx & 31;
  int qt = (grp == 0) ? q0 : (grp == 1) ? 15 - q0 : (grp == 2) ? 16 + q0 : 31 - q0;
  int kvh = h >> 2;
  float mfix = bound[0];   // uniform softmax max (log2 domain)

  int tid = threadIdx.x, w = tid >> 6, lane = tid & 63;
  int fr = lane & 15, hi = lane >> 4, fk = hi * 8;
  const u16* qbase = Qg + ((size_t)h * 2048 + qt * 64 + w * 16 + fr) * 64;
  short8 qf0 = *(const short8*)(qbase + fk);
  short8 qf1 = *(const short8*)(qbase + 32 + fk);
  f32x4 o[4] = {};
  float lrow = 0.0f;   // per-lane partial sum; reduced once after the loop

  // staging thread mapping
  int key0 = tid >> 3, c0 = tid & 7;                 // K: keys 0..31 (+32 second chunk)
  int kp = tid & 31, dg = tid >> 5, d0v = dg * 8;    // V: key pair 2kp,2kp+1, d rows d0v..d0v+7
  const u16* Kbase = Kg + (size_t)kvh * 2048 * 64;
  const u16* Vbase = Vg + (size_t)kvh * 2048 * 64;

  auto stage_load = [&](int kt2, short8& k0, short8& k1, short8& v0, short8& v1) {
    const u16* kb = Kbase + (size_t)kt2 * 64 * 64;
    k0 = *(const short8*)(kb + key0 * 64 + c0 * 8);
    k1 = *(const short8*)(kb + (32 + key0) * 64 + c0 * 8);
    const u16* vb = Vbase + (size_t)kt2 * 64 * 64 + (size_t)(2 * kp) * 64 + d0v;
    v0 = *(const short8*)vb;
    v1 = *(const short8*)(vb + 64);
  };
  auto stage_write = [&](short8 k0, short8 k1, short8 v0, short8 v1) {
    int offA = (key0 * 128 + c0 * 16) ^ ((key0 & 7) << 4);
    int offB = ((32 + key0) * 128 + c0 * 16) ^ ((key0 & 7) << 4);
    *(short8*)(KsB + offA) = k0;
    *(short8*)(KsB + offB) = k1;
#pragma unroll
    for (int j = 0; j < 8; ++j) {
      uint32_t pk = (uint32_t)(u16)v0[j] | ((uint32_t)(u16)v1[j] << 16);
      int d = d0v + j;
      int off = (d * 128 + kp * 4) ^ ((j & 7) << 4);   // d&7 == j
      *(uint32_t*)(VsB + off) = pk;
    }
  };

  short8 kA0, kA1, vA0, vA1, kB0, kB1, vB0, vB1;
  stage_load(0, kA0, kA1, vA0, vA1);

  uint32_t* Pw = &Ps[w][0];
  int swzr = (fr & 7) << 4;   // row-XOR for fragment reads
  int qrow = qt * 64 + w * 16 + fr;

  for (int kt = 0; kt <= qt; ++kt) {
    bool diag = (kt == qt);
    if ((kt & 1) == 0) stage_write(kA0, kA1, vA0, vA1);
    else               stage_write(kB0, kB1, vB0, vB1);
    __syncthreads();
    if (!diag) {   // prefetch next tile; lands under compute
      if ((kt & 1) == 0) stage_load(kt + 1, kB0, kB1, vB0, vB1);
      else               stage_load(kt + 1, kA0, kA1, vA0, vA1);
    }
    // S^T = K Q^T : lane (fr,hi) holds S[key=kt*64+g*16+hi*4+r][q-row=w*16+fr], log2 units
    f32x4 s4[4] = {};
    __builtin_amdgcn_s_setprio(1);
#pragma unroll
    for (int g = 0; g < 4; ++g) {
      int rb = (g * 16 + fr) * 128;
      short8 b0 = *(const short8*)(KsB + ((rb + hi * 16) ^ swzr));
      short8 b1 = *(const short8*)(KsB + ((rb + 64 + hi * 16) ^ swzr));
      s4[g] = __builtin_amdgcn_mfma_f32_16x16x32_bf16(b0, qf0, s4[g], 0, 0, 0);
      s4[g] = __builtin_amdgcn_mfma_f32_16x16x32_bf16(b1, qf1, s4[g], 0, 0, 0);
    }
    __builtin_amdgcn_s_setprio(0);
    // causal mask: only the diagonal tile crosses q==k
    if (diag) {
      int kbase = kt * 64 + hi * 4;
#pragma unroll
      for (int g = 0; g < 4; ++g)
#pragma unroll
        for (int r = 0; r < 4; ++r)
          if (kbase + g * 16 + r > qrow) s4[g][r] = -1e30f;
    }
    // P = exp2(S - mfix), lane-parallel; cvt_pk pack; per-lane partial l
#pragma unroll
    for (int g = 0; g < 4; ++g) {
      float p0 = exp2f(s4[g][0] - mfix);
      float p1 = exp2f(s4[g][1] - mfix);
      float p2 = exp2f(s4[g][2] - mfix);
      float p3 = exp2f(s4[g][3] - mfix);
      lrow += (p0 + p1) + (p2 + p3);
      uint2 pk = make_uint2(pack_bf16x2(p0, p1), pack_bf16x2(p2, p3));
      *(uint2*)&Pw[fr * 36 + g * 8 + hi * 2] = pk;   // b64
    }
    asm volatile("s_waitcnt lgkmcnt(0)" ::: "memory");  // P writes land (wave-local)
    // O += P V  (A-operand read back: u32 stride 36 -> b128 slot stride 9, conflict-free)
    short8 pa0 = *(const short8*)&Pw[fr * 36 + hi * 4];
    short8 pa1 = *(const short8*)&Pw[fr * 36 + 16 + hi * 4];
    __builtin_amdgcn_s_setprio(1);
#pragma unroll
    for (int g2 = 0; g2 < 4; ++g2) {
      int rb = (g2 * 16 + fr) * 128;
      short8 vb0 = *(const short8*)(VsB + ((rb + hi * 16) ^ swzr));
      short8 vb1 = *(const short8*)(VsB + ((rb + 64 + hi * 16) ^ swzr));
      o[g2] = __builtin_amdgcn_mfma_f32_16x16x32_bf16(pa0, vb0, o[g2], 0, 0, 0);
      o[g2] = __builtin_amdgcn_mfma_f32_16x16x32_bf16(pa1, vb1, o[g2], 0, 0, 0);
    }
    __builtin_amdgcn_s_setprio(0);
    __syncthreads();
  }
  // one l-reduction for the whole kernel
  float rtot = lrow;
  rtot += __shfl_xor(rtot, 16);
  rtot += __shfl_xor(rtot, 32);
#pragma unroll
  for (int r = 0; r < 4; ++r) {
    float li = __shfl(rtot, hi * 4 + r);
    float inv = 1.0f / li;
    size_t rowoff = (size_t)(qt * 64 + w * 16 + hi * 4 + r) * 2048 + h * 64;
#pragma unroll
    for (int g2 = 0; g2 < 4; ++g2)
      att[rowoff + g2 * 16 + fr] = f2bf(o[g2][r] * inv);
  }
}

extern "C" void kernel_launch(void* const* d_in, const int* in_sizes, int n_in,
                              void* d_out, int out_size, void* d_ws, size_t ws_size,
                              hipStream_t stream) {
  const float* x    = (const float*)d_in[0];
  const float* fc   = (const float*)d_in[1];
  const float* fs   = (const float*)d_in[2];
  // d_in[3] = mask (causal, regenerated in-kernel)
  const float* wq   = (const float*)d_in[4];
  const float* wq_b = (const float*)d_in[5];
  const float* wk   = (const float*)d_in[6];
  const float* wk_b = (const float*)d_in[7];
  const float* wv   = (const float*)d_in[8];
  const float* wv_b = (const float*)d_in[9];
  const float* wo   = (const float*)d_in[10];
  const float* wo_b = (const float*)d_in[11];
  const float* qn   = (const float*)d_in[12];
  const float* kn   = (const float*)d_in[13];
  float* out = (float*)d_out;

  char* ws = (char*)d_ws;
  u16*  xb    = (u16*)(ws);                          //  8 MB  x bf16 [2048][2048]
  u16*  wqkvT = (u16*)(ws + (size_t)(8  << 20));     // 12 MB  [3072][2048] bf16
  u16*  woT   = (u16*)(ws + (size_t)(20 << 20));     //  8 MB  [2048][2048] bf16
  float* qkv  = (float*)(ws + (size_t)(28 << 20));   // 24 MB  [2048][3072] f32
  u16*  Qg    = (u16*)(ws + (size_t)(52 << 20));     //  8 MB  [32][2048][64]
  u16*  Kg    = (u16*)(ws + (size_t)(60 << 20));     //  2 MB  [8][2048][64]
  u16*  Vg    = (u16*)(ws + (size_t)(62 << 20));     //  2 MB  [8][2048][64]
  u16*  att   = (u16*)(ws + (size_t)(64 << 20));     //  8 MB  [2048][2048]
  float* bnd  = qkv;   // qkv buffer is dead after qkv_post; reuse 4 bytes

  conv_bf16<<<4096, 256, 0, stream>>>(x, xb, 1048576);
  transpose_conv<<<dim3(32, 32), 256, 0, stream>>>(wq, wqkvT, 2048, 2048);
  transpose_conv<<<dim3(8, 32),  256, 0, stream>>>(wk, wqkvT + (size_t)2048 * 2048, 2048, 512);
  transpose_conv<<<dim3(8, 32),  256, 0, stream>>>(wv, wqkvT + (size_t)2560 * 2048, 2048, 512);
  transpose_conv<<<dim3(32, 32), 256, 0, stream>>>(wo, woT, 2048, 2048);
  gemm_bt<<<16 * 24, 256, 0, stream>>>(xb, wqkvT, qkv, (const float*)nullptr, 2048, 3072, 2048);
  qkv_post<<<24576, 256, 0, stream>>>(qkv, wq_b, wk_b, wv_b, qn, kn, fc, fs, Qg, Kg, Vg);
  bound_kernel<<<1, 64, 0, stream>>>(qn, kn, bnd);
  attn_kernel<<<1024, 256, 0, stream>>>(Qg, Kg, Vg, bnd, att);
  gemm_bt<<<16 * 16, 256, 0, stream>>>(att, woT, out, wo_b, 2048, 2048, 2048);
}

// Round 9
// 190.177 us; speedup vs baseline: 1.2120x; 1.0014x over previous
//
#include <hip/hip_runtime.h>
#include <hip/hip_bf16.h>
#include <cstdint>

typedef unsigned short u16;
typedef __attribute__((ext_vector_type(8))) short short8;   // 8 x bf16 fragment
typedef __attribute__((ext_vector_type(4))) float f32x4;

__device__ __forceinline__ u16 f2bf(float f) {
  union { float f; uint32_t u; } c; c.f = f;
  return (u16)((c.u + 0x7FFFu + ((c.u >> 16) & 1u)) >> 16);
}

__device__ __forceinline__ uint32_t pack_bf16x2(float a, float b) {
  union { __hip_bfloat162 h; uint32_t u; } c;
  c.h = __float22bfloat162_rn(make_float2(a, b));   // v_cvt_pk_bf16_f32
  return c.u;
}

// ---------- fp32 -> bf16 elementwise (4 per thread) ----------
__global__ __launch_bounds__(256) void conv_bf16(const float* __restrict__ in,
                                                 u16* __restrict__ out, int n4) {
  int i = blockIdx.x * 256 + threadIdx.x;
  if (i >= n4) return;
  float4 v = ((const float4*)in)[i];
  ((ushort4*)out)[i] = make_ushort4(f2bf(v.x), f2bf(v.y), f2bf(v.z), f2bf(v.w));
}

// ---------- transpose + convert: in [K][N] f32 -> out [N][K] bf16 ----------
__global__ __launch_bounds__(256) void transpose_conv(const float* __restrict__ in,
                                                      u16* __restrict__ out, int K, int N) {
  __shared__ float tile[64][65];
  int n0 = blockIdx.x * 64, k0 = blockIdx.y * 64;
  int t = threadIdx.x;
  int a = t & 63, b4 = t >> 6;
#pragma unroll
  for (int j = 0; j < 16; ++j) {
    int kk = j * 4 + b4;
    tile[kk][a] = in[(size_t)(k0 + kk) * N + n0 + a];
  }
  __syncthreads();
#pragma unroll
  for (int j = 0; j < 16; ++j) {
    int nn = j * 4 + b4;
    out[(size_t)(n0 + nn) * K + k0 + a] = f2bf(tile[a][nn]);
  }
}

// ---------- bf16 GEMM: C[M][N] (f32,+bias) = A[M][K] * Bt[N][K]^T ----------
// 128x128 tile, BK=32, 2-phase double-buffered LDS, XCD-swizzled grid.
__global__ __launch_bounds__(256, 3) void gemm_bt(const u16* __restrict__ A,
                                                  const u16* __restrict__ Bt,
                                                  float* __restrict__ C,
                                                  const float* __restrict__ bias,
                                                  int M, int N, int K) {
  __shared__ alignas(16) u16 As[2][128 * 32];
  __shared__ alignas(16) u16 Bs[2][128 * 32];
  int nb = N >> 7;
  // bijective XCD swizzle (grid % 8 == 0 for both call sites)
  int nwg = gridDim.x;
  int cpx = nwg >> 3;
  int bid = blockIdx.x;
  int swz = (bid & 7) * cpx + (bid >> 3);
  int m0 = (swz / nb) << 7;
  int n0 = (swz % nb) << 7;
  int tid = threadIdx.x;
  int w = tid >> 6, lane = tid & 63;
  int wr = w >> 1, wc = w & 1;
  int fr = lane & 15, hi = lane >> 4, fk = hi * 8;
  int r0 = tid >> 2, c0 = tid & 3;

  auto STAGE = [&](int buf, int kt) {
#pragma unroll
    for (int b = 0; b < 2; ++b) {
      int r = (b << 6) + r0;
      const u16* ga = A + (size_t)(m0 + r) * K + kt + c0 * 8;
      const u16* gb = Bt + (size_t)(n0 + r) * K + kt + c0 * 8;
      u16* la = &As[buf][(size_t)(b * 256 + w * 64) * 8];   // wave-uniform base
      u16* lb = &Bs[buf][(size_t)(b * 256 + w * 64) * 8];
      __builtin_amdgcn_global_load_lds((const __attribute__((address_space(1))) void*)ga,
                                       (__attribute__((address_space(3))) void*)la, 16, 0, 0);
      __builtin_amdgcn_global_load_lds((const __attribute__((address_space(1))) void*)gb,
                                       (__attribute__((address_space(3))) void*)lb, 16, 0, 0);
    }
  };

  f32x4 acc[4][4] = {};
  STAGE(0, 0);
  __syncthreads();
  int cur = 0;
  for (int kt = 0; kt < K; kt += 32) {
    if (kt + 32 < K) STAGE(cur ^ 1, kt + 32);   // overlap next-tile HBM with compute
    short8 af[4], bfr[4];
#pragma unroll
    for (int m = 0; m < 4; ++m) af[m] = *(const short8*)&As[cur][(wr * 64 + m * 16 + fr) * 32 + fk];
#pragma unroll
    for (int n = 0; n < 4; ++n) bfr[n] = *(const short8*)&Bs[cur][(wc * 64 + n * 16 + fr) * 32 + fk];
#pragma unroll
    for (int m = 0; m < 4; ++m)
#pragma unroll
      for (int n = 0; n < 4; ++n)
        acc[m][n] = __builtin_amdgcn_mfma_f32_16x16x32_bf16(af[m], bfr[n], acc[m][n], 0, 0, 0);
    __syncthreads();   // drains vmcnt(0)+lgkmcnt(0): staged tile ready, reads done
    cur ^= 1;
  }
#pragma unroll
  for (int m = 0; m < 4; ++m) {
#pragma unroll
    for (int n = 0; n < 4; ++n) {
      int gcol = n0 + wc * 64 + n * 16 + fr;
      float bv = bias ? bias[gcol] : 0.0f;
#pragma unroll
      for (int r = 0; r < 4; ++r) {
        int grow = m0 + wr * 64 + m * 16 + hi * 4 + r;
        C[(size_t)grow * N + gcol] = acc[m][n][r] + bv;
      }
    }
  }
}

// ---------- QKV postprocess: bias + RMSNorm + RoPE + layout [head][t][64] bf16 ----------
// one wave per (t, head); heads 0..31 = Q (pre-scaled by 0.125*log2e), 32..39 = K, 40..47 = V
__global__ __launch_bounds__(256) void qkv_post(const float* __restrict__ qkv,
    const float* __restrict__ wq_b, const float* __restrict__ wk_b, const float* __restrict__ wv_b,
    const float* __restrict__ qn_w, const float* __restrict__ kn_w,
    const float* __restrict__ fc, const float* __restrict__ fs,
    u16* __restrict__ Qg, u16* __restrict__ Kg, u16* __restrict__ Vg) {
  int gid = blockIdx.x * 256 + threadIdx.x;
  int wave = gid >> 6, d = gid & 63;
  int t = wave / 48, hh = wave % 48;
  float v;
  if (hh < 32)       v = qkv[(size_t)t * 3072 + hh * 64 + d] + wq_b[hh * 64 + d];
  else if (hh < 40)  v = qkv[(size_t)t * 3072 + 2048 + (hh - 32) * 64 + d] + wk_b[(hh - 32) * 64 + d];
  else               v = qkv[(size_t)t * 3072 + 2560 + (hh - 40) * 64 + d] + wv_b[(hh - 40) * 64 + d];
  if (hh < 40) {
    float sq = v * v;
#pragma unroll
    for (int off = 32; off >= 1; off >>= 1) sq += __shfl_xor(sq, off);
    float rr = rsqrtf(sq * (1.0f / 64.0f) + 1e-5f);
    float wn = (hh < 32) ? qn_w[d] * 0.18033688f : kn_w[d];   // Q: fold 0.125*log2(e)
    v = v * rr * wn;
    float part = __shfl_xor(v, 1);
    float c = fc[t * 32 + (d >> 1)];
    float s = fs[t * 32 + (d >> 1)];
    v = (d & 1) ? (part * s + v * c) : (v * c - part * s);
  }
  u16 bv = f2bf(v);
  if (hh < 32)       Qg[((size_t)hh * 2048 + t) * 64 + d] = bv;
  else if (hh < 40)  Kg[((size_t)(hh - 32) * 2048 + t) * 64 + d] = bv;
  else               Vg[((size_t)(hh - 40) * 2048 + t) * 64 + d] = bv;
}

// ---------- causal GQA flash attention (v6: 4 blocks/CU, in-kernel bound) ----------
__global__ __launch_bounds__(256, 4) void attn_kernel(const u16* __restrict__ Qg,
                                                      const u16* __restrict__ Kg,
                                                      const u16* __restrict__ Vg,
                                                      const float* __restrict__ qn_w,
                                                      const float* __restrict__ kn_w,
                                                      u16* __restrict__ att) {
  __shared__ alignas(16) u16 Ks[64 * 64];            // [key][d], XOR-swizzled rows
  __shared__ alignas(16) u16 Vs[64 * 64];            // [d][key], XOR-swizzled rows
  __shared__ alignas(16) uint32_t Ps[4][16 * 36];    // per-wave P: [q=fr][key-pair], stride 36
  char* KsB = (char*)Ks;
  char* VsB = (char*)Vs;

  // balanced remap: each CU's round-robin set {q0,15-q0,16+q0,31-q0} sums uniform
  int bid = blockIdx.x;
  int grp = bid >> 8, idx = bid & 255;
  int q0 = idx >> 5, h = idx & 31;
  int qt = (grp == 0) ? q0 : (grp == 1) ? 15 - q0 : (grp == 2) ? 16 + q0 : 31 - q0;
  int kvh = h >> 2;

  int tid = threadIdx.x, w = tid >> 6, lane = tid & 63;
  int fr = lane & 15, hi = lane >> 4, fk = hi * 8;

  // softmax upper bound: S_log2 <= 11.5416 * max|qn| * max|kn|  (per-wave, ~15 ops once)
  float ba = fabsf(qn_w[lane]), bb = fabsf(kn_w[lane]);
#pragma unroll
  for (int off = 32; off >= 1; off >>= 1) {
    ba = fmaxf(ba, __shfl_xor(ba, off));
    bb = fmaxf(bb, __shfl_xor(bb, off));
  }
  float mfix = 11.5416222f * ba * bb;   // uniform softmax max (log2 domain)

  const u16* qbase = Qg + ((size_t)h * 2048 + qt * 64 + w * 16 + fr) * 64;
  short8 qf0 = *(const short8*)(qbase + fk);
  short8 qf1 = *(const short8*)(qbase + 32 + fk);
  f32x4 o[4] = {};
  float lrow = 0.0f;   // per-lane partial sum; reduced once after the loop

  // staging thread mapping
  int key0 = tid >> 3, c0 = tid & 7;                 // K: keys 0..31 (+32 second chunk)
  int kp = tid & 31, dg = tid >> 5, d0v = dg * 8;    // V: key pair 2kp,2kp+1, d rows d0v..d0v+7
  const u16* Kbase = Kg + (size_t)kvh * 2048 * 64;
  const u16* Vbase = Vg + (size_t)kvh * 2048 * 64;

  auto stage_load = [&](int kt2, short8& k0, short8& k1, short8& v0, short8& v1) {
    const u16* kb = Kbase + (size_t)kt2 * 64 * 64;
    k0 = *(const short8*)(kb + key0 * 64 + c0 * 8);
    k1 = *(const short8*)(kb + (32 + key0) * 64 + c0 * 8);
    const u16* vb = Vbase + (size_t)kt2 * 64 * 64 + (size_t)(2 * kp) * 64 + d0v;
    v0 = *(const short8*)vb;
    v1 = *(const short8*)(vb + 64);
  };
  auto stage_write = [&](short8 k0, short8 k1, short8 v0, short8 v1) {
    int offA = (key0 * 128 + c0 * 16) ^ ((key0 & 7) << 4);
    int offB = ((32 + key0) * 128 + c0 * 16) ^ ((key0 & 7) << 4);
    *(short8*)(KsB + offA) = k0;
    *(short8*)(KsB + offB) = k1;
#pragma unroll
    for (int j = 0; j < 8; ++j) {
      uint32_t pk = (uint32_t)(u16)v0[j] | ((uint32_t)(u16)v1[j] << 16);
      int d = d0v + j;
      int off = (d * 128 + kp * 4) ^ ((j & 7) << 4);   // d&7 == j
      *(uint32_t*)(VsB + off) = pk;
    }
  };

  short8 kA0, kA1, vA0, vA1, kB0, kB1, vB0, vB1;
  stage_load(0, kA0, kA1, vA0, vA1);

  uint32_t* Pw = &Ps[w][0];
  int swzr = (fr & 7) << 4;   // row-XOR for fragment reads
  int qrow = qt * 64 + w * 16 + fr;

  for (int kt = 0; kt <= qt; ++kt) {
    bool diag = (kt == qt);
    if ((kt & 1) == 0) stage_write(kA0, kA1, vA0, vA1);
    else               stage_write(kB0, kB1, vB0, vB1);
    __syncthreads();
    if (!diag) {   // prefetch next tile; lands under compute
      if ((kt & 1) == 0) stage_load(kt + 1, kB0, kB1, vB0, vB1);
      else               stage_load(kt + 1, kA0, kA1, vA0, vA1);
    }
    // S^T = K Q^T : lane (fr,hi) holds S[key=kt*64+g*16+hi*4+r][q-row=w*16+fr], log2 units
    f32x4 s4[4] = {};
    __builtin_amdgcn_s_setprio(1);
#pragma unroll
    for (int g = 0; g < 4; ++g) {
      int rb = (g * 16 + fr) * 128;
      short8 b0 = *(const short8*)(KsB + ((rb + hi * 16) ^ swzr));
      short8 b1 = *(const short8*)(KsB + ((rb + 64 + hi * 16) ^ swzr));
      s4[g] = __builtin_amdgcn_mfma_f32_16x16x32_bf16(b0, qf0, s4[g], 0, 0, 0);
      s4[g] = __builtin_amdgcn_mfma_f32_16x16x32_bf16(b1, qf1, s4[g], 0, 0, 0);
    }
    __builtin_amdgcn_s_setprio(0);
    // causal mask: only the diagonal tile crosses q==k
    if (diag) {
      int kbase = kt * 64 + hi * 4;
#pragma unroll
      for (int g = 0; g < 4; ++g)
#pragma unroll
        for (int r = 0; r < 4; ++r)
          if (kbase + g * 16 + r > qrow) s4[g][r] = -1e30f;
    }
    // P = exp2(S - mfix), lane-parallel; cvt_pk pack; per-lane partial l
#pragma unroll
    for (int g = 0; g < 4; ++g) {
      float p0 = exp2f(s4[g][0] - mfix);
      float p1 = exp2f(s4[g][1] - mfix);
      float p2 = exp2f(s4[g][2] - mfix);
      float p3 = exp2f(s4[g][3] - mfix);
      lrow += (p0 + p1) + (p2 + p3);
      uint2 pk = make_uint2(pack_bf16x2(p0, p1), pack_bf16x2(p2, p3));
      *(uint2*)&Pw[fr * 36 + g * 8 + hi * 2] = pk;   // b64
    }
    asm volatile("s_waitcnt lgkmcnt(0)" ::: "memory");  // P writes land (wave-local)
    // O += P V  (A-operand read back: u32 stride 36 -> b128 slot stride 9, conflict-free)
    short8 pa0 = *(const short8*)&Pw[fr * 36 + hi * 4];
    short8 pa1 = *(const short8*)&Pw[fr * 36 + 16 + hi * 4];
    __builtin_amdgcn_s_setprio(1);
#pragma unroll
    for (int g2 = 0; g2 < 4; ++g2) {
      int rb = (g2 * 16 + fr) * 128;
      short8 vb0 = *(const short8*)(VsB + ((rb + hi * 16) ^ swzr));
      short8 vb1 = *(const short8*)(VsB + ((rb + 64 + hi * 16) ^ swzr));
      o[g2] = __builtin_amdgcn_mfma_f32_16x16x32_bf16(pa0, vb0, o[g2], 0, 0, 0);
      o[g2] = __builtin_amdgcn_mfma_f32_16x16x32_bf16(pa1, vb1, o[g2], 0, 0, 0);
    }
    __builtin_amdgcn_s_setprio(0);
    __syncthreads();
  }
  // one l-reduction for the whole kernel
  float rtot = lrow;
  rtot += __shfl_xor(rtot, 16);
  rtot += __shfl_xor(rtot, 32);
#pragma unroll
  for (int r = 0; r < 4; ++r) {
    float li = __shfl(rtot, hi * 4 + r);
    float inv = 1.0f / li;
    size_t rowoff = (size_t)(qt * 64 + w * 16 + hi * 4 + r) * 2048 + h * 64;
#pragma unroll
    for (int g2 = 0; g2 < 4; ++g2)
      att[rowoff + g2 * 16 + fr] = f2bf(o[g2][r] * inv);
  }
}

extern "C" void kernel_launch(void* const* d_in, const int* in_sizes, int n_in,
                              void* d_out, int out_size, void* d_ws, size_t ws_size,
                              hipStream_t stream) {
  const float* x    = (const float*)d_in[0];
  const float* fc   = (const float*)d_in[1];
  const float* fs   = (const float*)d_in[2];
  // d_in[3] = mask (causal, regenerated in-kernel)
  const float* wq   = (const float*)d_in[4];
  const float* wq_b = (const float*)d_in[5];
  const float* wk   = (const float*)d_in[6];
  const float* wk_b = (const float*)d_in[7];
  const float* wv   = (const float*)d_in[8];
  const float* wv_b = (const float*)d_in[9];
  const float* wo   = (const float*)d_in[10];
  const float* wo_b = (const float*)d_in[11];
  const float* qn   = (const float*)d_in[12];
  const float* kn   = (const float*)d_in[13];
  float* out = (float*)d_out;

  char* ws = (char*)d_ws;
  u16*  xb    = (u16*)(ws);                          //  8 MB  x bf16 [2048][2048]
  u16*  wqkvT = (u16*)(ws + (size_t)(8  << 20));     // 12 MB  [3072][2048] bf16
  u16*  woT   = (u16*)(ws + (size_t)(20 << 20));     //  8 MB  [2048][2048] bf16
  float* qkv  = (float*)(ws + (size_t)(28 << 20));   // 24 MB  [2048][3072] f32
  u16*  Qg    = (u16*)(ws + (size_t)(52 << 20));     //  8 MB  [32][2048][64]
  u16*  Kg    = (u16*)(ws + (size_t)(60 << 20));     //  2 MB  [8][2048][64]
  u16*  Vg    = (u16*)(ws + (size_t)(62 << 20));     //  2 MB  [8][2048][64]
  u16*  att   = (u16*)(ws + (size_t)(64 << 20));     //  8 MB  [2048][2048]

  conv_bf16<<<4096, 256, 0, stream>>>(x, xb, 1048576);
  transpose_conv<<<dim3(32, 32), 256, 0, stream>>>(wq, wqkvT, 2048, 2048);
  transpose_conv<<<dim3(8, 32),  256, 0, stream>>>(wk, wqkvT + (size_t)2048 * 2048, 2048, 512);
  transpose_conv<<<dim3(8, 32),  256, 0, stream>>>(wv, wqkvT + (size_t)2560 * 2048, 2048, 512);
  transpose_conv<<<dim3(32, 32), 256, 0, stream>>>(wo, woT, 2048, 2048);
  gemm_bt<<<16 * 24, 256, 0, stream>>>(xb, wqkvT, qkv, (const float*)nullptr, 2048, 3072, 2048);
  qkv_post<<<24576, 256, 0, stream>>>(qkv, wq_b, wk_b, wv_b, qn, kn, fc, fs, Qg, Kg, Vg);
  attn_kernel<<<1024, 256, 0, stream>>>(Qg, Kg, Vg, qn, kn, att);
  gemm_bt<<<16 * 16, 256, 0, stream>>>(att, woT, out, wo_b, 2048, 2048, 2048);
}

// Round 10
// 177.095 us; speedup vs baseline: 1.3015x; 1.0739x over previous
//
#include <hip/hip_runtime.h>
#include <hip/hip_bf16.h>
#include <cstdint>

typedef unsigned short u16;
typedef __attribute__((ext_vector_type(8))) short short8;   // 8 x bf16 fragment
typedef __attribute__((ext_vector_type(4))) float f32x4;

__device__ __forceinline__ u16 f2bf(float f) {
  union { float f; uint32_t u; } c; c.f = f;
  return (u16)((c.u + 0x7FFFu + ((c.u >> 16) & 1u)) >> 16);
}

__device__ __forceinline__ uint32_t pack_bf16x2(float a, float b) {
  union { __hip_bfloat162 h; uint32_t u; } c;
  c.h = __float22bfloat162_rn(make_float2(a, b));   // v_cvt_pk_bf16_f32
  return c.u;
}

// ---------- fp32 -> bf16 elementwise (4 per thread) ----------
__global__ __launch_bounds__(256) void conv_bf16(const float* __restrict__ in,
                                                 u16* __restrict__ out, int n4) {
  int i = blockIdx.x * 256 + threadIdx.x;
  if (i >= n4) return;
  float4 v = ((const float4*)in)[i];
  ((ushort4*)out)[i] = make_ushort4(f2bf(v.x), f2bf(v.y), f2bf(v.z), f2bf(v.w));
}

// ---------- transpose + convert: in [K][N] f32 -> out [N][K] bf16 ----------
__global__ __launch_bounds__(256) void transpose_conv(const float* __restrict__ in,
                                                      u16* __restrict__ out, int K, int N) {
  __shared__ float tile[64][65];
  int n0 = blockIdx.x * 64, k0 = blockIdx.y * 64;
  int t = threadIdx.x;
  int a = t & 63, b4 = t >> 6;
#pragma unroll
  for (int j = 0; j < 16; ++j) {
    int kk = j * 4 + b4;
    tile[kk][a] = in[(size_t)(k0 + kk) * N + n0 + a];
  }
  __syncthreads();
#pragma unroll
  for (int j = 0; j < 16; ++j) {
    int nn = j * 4 + b4;
    out[(size_t)(n0 + nn) * K + k0 + a] = f2bf(tile[a][nn]);
  }
}

// ---------- bf16 GEMM: C[M][N] (f32,+bias) = A[M][K] * Bt[N][K]^T ----------
// 64x128 tile, BK=32, 2-phase dbuf, XCD-swizzled grid. Small tiles -> 2-3 blocks/CU
// exactly (M=2048 shapes), cross-block overlap hides barrier drain.
__global__ __launch_bounds__(256, 4) void gemm_bt(const u16* __restrict__ A,
                                                  const u16* __restrict__ Bt,
                                                  float* __restrict__ C,
                                                  const float* __restrict__ bias,
                                                  int M, int N, int K) {
  __shared__ alignas(16) u16 As[2][64 * 32];
  __shared__ alignas(16) u16 Bs[2][128 * 32];
  int nb = N >> 7;
  // bijective XCD swizzle (grid % 8 == 0 for both call sites)
  int nwg = gridDim.x;
  int cpx = nwg >> 3;
  int bid = blockIdx.x;
  int swz = (bid & 7) * cpx + (bid >> 3);
  int m0 = (swz / nb) << 6;
  int n0 = (swz % nb) << 7;
  int tid = threadIdx.x;
  int w = tid >> 6, lane = tid & 63;
  int wr = w >> 1, wc = w & 1;
  int fr = lane & 15, hi = lane >> 4, fk = hi * 8;
  int r0 = tid >> 2, c0 = tid & 3;

  auto STAGE = [&](int buf, int kt) {
    // A tile 64x32: one 16B chunk per thread
    const u16* ga = A + (size_t)(m0 + r0) * K + kt + c0 * 8;
    u16* la = &As[buf][(size_t)(w * 64) * 8];   // wave-uniform base
    __builtin_amdgcn_global_load_lds((const __attribute__((address_space(1))) void*)ga,
                                     (__attribute__((address_space(3))) void*)la, 16, 0, 0);
    // B tile 128x32: two chunks per thread
#pragma unroll
    for (int b = 0; b < 2; ++b) {
      int r = (b << 6) + r0;
      const u16* gb = Bt + (size_t)(n0 + r) * K + kt + c0 * 8;
      u16* lb = &Bs[buf][(size_t)(b * 256 + w * 64) * 8];
      __builtin_amdgcn_global_load_lds((const __attribute__((address_space(1))) void*)gb,
                                       (__attribute__((address_space(3))) void*)lb, 16, 0, 0);
    }
  };

  f32x4 acc[2][4] = {};
  STAGE(0, 0);
  __syncthreads();
  int cur = 0;
  for (int kt = 0; kt < K; kt += 32) {
    if (kt + 32 < K) STAGE(cur ^ 1, kt + 32);   // overlap next-tile loads with compute
    short8 af[2], bfr[4];
#pragma unroll
    for (int m = 0; m < 2; ++m) af[m] = *(const short8*)&As[cur][(wr * 32 + m * 16 + fr) * 32 + fk];
#pragma unroll
    for (int n = 0; n < 4; ++n) bfr[n] = *(const short8*)&Bs[cur][(wc * 64 + n * 16 + fr) * 32 + fk];
#pragma unroll
    for (int m = 0; m < 2; ++m)
#pragma unroll
      for (int n = 0; n < 4; ++n)
        acc[m][n] = __builtin_amdgcn_mfma_f32_16x16x32_bf16(af[m], bfr[n], acc[m][n], 0, 0, 0);
    __syncthreads();   // drains vmcnt(0)+lgkmcnt(0): staged tile ready, reads done
    cur ^= 1;
  }
#pragma unroll
  for (int m = 0; m < 2; ++m) {
#pragma unroll
    for (int n = 0; n < 4; ++n) {
      int gcol = n0 + wc * 64 + n * 16 + fr;
      float bv = bias ? bias[gcol] : 0.0f;
#pragma unroll
      for (int r = 0; r < 4; ++r) {
        int grow = m0 + wr * 32 + m * 16 + hi * 4 + r;
        C[(size_t)grow * N + gcol] = acc[m][n][r] + bv;
      }
    }
  }
}

// ---------- QKV postprocess: bias + RMSNorm + RoPE + layout [head][t][64] bf16 ----------
// one wave per (t, head); heads 0..31 = Q (pre-scaled by 0.125*log2e), 32..39 = K, 40..47 = V
__global__ __launch_bounds__(256) void qkv_post(const float* __restrict__ qkv,
    const float* __restrict__ wq_b, const float* __restrict__ wk_b, const float* __restrict__ wv_b,
    const float* __restrict__ qn_w, const float* __restrict__ kn_w,
    const float* __restrict__ fc, const float* __restrict__ fs,
    u16* __restrict__ Qg, u16* __restrict__ Kg, u16* __restrict__ Vg) {
  int gid = blockIdx.x * 256 + threadIdx.x;
  int wave = gid >> 6, d = gid & 63;
  int t = wave / 48, hh = wave % 48;
  float v;
  if (hh < 32)       v = qkv[(size_t)t * 3072 + hh * 64 + d] + wq_b[hh * 64 + d];
  else if (hh < 40)  v = qkv[(size_t)t * 3072 + 2048 + (hh - 32) * 64 + d] + wk_b[(hh - 32) * 64 + d];
  else               v = qkv[(size_t)t * 3072 + 2560 + (hh - 40) * 64 + d] + wv_b[(hh - 40) * 64 + d];
  if (hh < 40) {
    float sq = v * v;
#pragma unroll
    for (int off = 32; off >= 1; off >>= 1) sq += __shfl_xor(sq, off);
    float rr = rsqrtf(sq * (1.0f / 64.0f) + 1e-5f);
    float wn = (hh < 32) ? qn_w[d] * 0.18033688f : kn_w[d];   // Q: fold 0.125*log2(e)
    v = v * rr * wn;
    float part = __shfl_xor(v, 1);
    float c = fc[t * 32 + (d >> 1)];
    float s = fs[t * 32 + (d >> 1)];
    v = (d & 1) ? (part * s + v * c) : (v * c - part * s);
  }
  u16 bv = f2bf(v);
  if (hh < 32)       Qg[((size_t)hh * 2048 + t) * 64 + d] = bv;
  else if (hh < 40)  Kg[((size_t)(hh - 32) * 2048 + t) * 64 + d] = bv;
  else               Vg[((size_t)(hh - 40) * 2048 + t) * 64 + d] = bv;
}

// ---------- causal GQA flash attention (v6: fixed-max, in-kernel bound) ----------
__global__ __launch_bounds__(256, 4) void attn_kernel(const u16* __restrict__ Qg,
                                                      const u16* __restrict__ Kg,
                                                      const u16* __restrict__ Vg,
                                                      const float* __restrict__ qn_w,
                                                      const float* __restrict__ kn_w,
                                                      u16* __restrict__ att) {
  __shared__ alignas(16) u16 Ks[64 * 64];            // [key][d], XOR-swizzled rows
  __shared__ alignas(16) u16 Vs[64 * 64];            // [d][key], XOR-swizzled rows
  __shared__ alignas(16) uint32_t Ps[4][16 * 36];    // per-wave P: [q=fr][key-pair], stride 36
  char* KsB = (char*)Ks;
  char* VsB = (char*)Vs;

  // balanced remap: each CU's round-robin set {q0,15-q0,16+q0,31-q0} sums uniform
  int bid = blockIdx.x;
  int grp = bid >> 8, idx = bid & 255;
  int q0 = idx >> 5, h = idx & 31;
  int qt = (grp == 0) ? q0 : (grp == 1) ? 15 - q0 : (grp == 2) ? 16 + q0 : 31 - q0;
  int kvh = h >> 2;

  int tid = threadIdx.x, w = tid >> 6, lane = tid & 63;
  int fr = lane & 15, hi = lane >> 4, fk = hi * 8;

  // softmax upper bound: S_log2 <= 11.5416 * max|qn| * max|kn|  (per-wave, ~15 ops once)
  float ba = fabsf(qn_w[lane]), bb = fabsf(kn_w[lane]);
#pragma unroll
  for (int off = 32; off >= 1; off >>= 1) {
    ba = fmaxf(ba, __shfl_xor(ba, off));
    bb = fmaxf(bb, __shfl_xor(bb, off));
  }
  float mfix = 11.5416222f * ba * bb;   // uniform softmax max (log2 domain)

  const u16* qbase = Qg + ((size_t)h * 2048 + qt * 64 + w * 16 + fr) * 64;
  short8 qf0 = *(const short8*)(qbase + fk);
  short8 qf1 = *(const short8*)(qbase + 32 + fk);
  f32x4 o[4] = {};
  float lrow = 0.0f;   // per-lane partial sum; reduced once after the loop

  // staging thread mapping
  int key0 = tid >> 3, c0 = tid & 7;                 // K: keys 0..31 (+32 second chunk)
  int kp = tid & 31, dg = tid >> 5, d0v = dg * 8;    // V: key pair 2kp,2kp+1, d rows d0v..d0v+7
  const u16* Kbase = Kg + (size_t)kvh * 2048 * 64;
  const u16* Vbase = Vg + (size_t)kvh * 2048 * 64;

  auto stage_load = [&](int kt2, short8& k0, short8& k1, short8& v0, short8& v1) {
    const u16* kb = Kbase + (size_t)kt2 * 64 * 64;
    k0 = *(const short8*)(kb + key0 * 64 + c0 * 8);
    k1 = *(const short8*)(kb + (32 + key0) * 64 + c0 * 8);
    const u16* vb = Vbase + (size_t)kt2 * 64 * 64 + (size_t)(2 * kp) * 64 + d0v;
    v0 = *(const short8*)vb;
    v1 = *(const short8*)(vb + 64);
  };
  auto stage_write = [&](short8 k0, short8 k1, short8 v0, short8 v1) {
    int offA = (key0 * 128 + c0 * 16) ^ ((key0 & 7) << 4);
    int offB = ((32 + key0) * 128 + c0 * 16) ^ ((key0 & 7) << 4);
    *(short8*)(KsB + offA) = k0;
    *(short8*)(KsB + offB) = k1;
#pragma unroll
    for (int j = 0; j < 8; ++j) {
      uint32_t pk = (uint32_t)(u16)v0[j] | ((uint32_t)(u16)v1[j] << 16);
      int d = d0v + j;
      int off = (d * 128 + kp * 4) ^ ((j & 7) << 4);   // d&7 == j
      *(uint32_t*)(VsB + off) = pk;
    }
  };

  short8 kA0, kA1, vA0, vA1, kB0, kB1, vB0, vB1;
  stage_load(0, kA0, kA1, vA0, vA1);

  uint32_t* Pw = &Ps[w][0];
  int swzr = (fr & 7) << 4;   // row-XOR for fragment reads
  int qrow = qt * 64 + w * 16 + fr;

  for (int kt = 0; kt <= qt; ++kt) {
    bool diag = (kt == qt);
    if ((kt & 1) == 0) stage_write(kA0, kA1, vA0, vA1);
    else               stage_write(kB0, kB1, vB0, vB1);
    __syncthreads();
    if (!diag) {   // prefetch next tile; lands under compute
      if ((kt & 1) == 0) stage_load(kt + 1, kB0, kB1, vB0, vB1);
      else               stage_load(kt + 1, kA0, kA1, vA0, vA1);
    }
    // S^T = K Q^T : lane (fr,hi) holds S[key=kt*64+g*16+hi*4+r][q-row=w*16+fr], log2 units
    f32x4 s4[4] = {};
    __builtin_amdgcn_s_setprio(1);
#pragma unroll
    for (int g = 0; g < 4; ++g) {
      int rb = (g * 16 + fr) * 128;
      short8 b0 = *(const short8*)(KsB + ((rb + hi * 16) ^ swzr));
      short8 b1 = *(const short8*)(KsB + ((rb + 64 + hi * 16) ^ swzr));
      s4[g] = __builtin_amdgcn_mfma_f32_16x16x32_bf16(b0, qf0, s4[g], 0, 0, 0);
      s4[g] = __builtin_amdgcn_mfma_f32_16x16x32_bf16(b1, qf1, s4[g], 0, 0, 0);
    }
    __builtin_amdgcn_s_setprio(0);
    // causal mask: only the diagonal tile crosses q==k
    if (diag) {
      int kbase = kt * 64 + hi * 4;
#pragma unroll
      for (int g = 0; g < 4; ++g)
#pragma unroll
        for (int r = 0; r < 4; ++r)
          if (kbase + g * 16 + r > qrow) s4[g][r] = -1e30f;
    }
    // P = exp2(S - mfix), lane-parallel; cvt_pk pack; per-lane partial l
#pragma unroll
    for (int g = 0; g < 4; ++g) {
      float p0 = exp2f(s4[g][0] - mfix);
      float p1 = exp2f(s4[g][1] - mfix);
      float p2 = exp2f(s4[g][2] - mfix);
      float p3 = exp2f(s4[g][3] - mfix);
      lrow += (p0 + p1) + (p2 + p3);
      uint2 pk = make_uint2(pack_bf16x2(p0, p1), pack_bf16x2(p2, p3));
      *(uint2*)&Pw[fr * 36 + g * 8 + hi * 2] = pk;   // b64
    }
    asm volatile("s_waitcnt lgkmcnt(0)" ::: "memory");  // P writes land (wave-local)
    // O += P V  (A-operand read back: u32 stride 36 -> b128 slot stride 9, conflict-free)
    short8 pa0 = *(const short8*)&Pw[fr * 36 + hi * 4];
    short8 pa1 = *(const short8*)&Pw[fr * 36 + 16 + hi * 4];
    __builtin_amdgcn_s_setprio(1);
#pragma unroll
    for (int g2 = 0; g2 < 4; ++g2) {
      int rb = (g2 * 16 + fr) * 128;
      short8 vb0 = *(const short8*)(VsB + ((rb + hi * 16) ^ swzr));
      short8 vb1 = *(const short8*)(VsB + ((rb + 64 + hi * 16) ^ swzr));
      o[g2] = __builtin_amdgcn_mfma_f32_16x16x32_bf16(pa0, vb0, o[g2], 0, 0, 0);
      o[g2] = __builtin_amdgcn_mfma_f32_16x16x32_bf16(pa1, vb1, o[g2], 0, 0, 0);
    }
    __builtin_amdgcn_s_setprio(0);
    __syncthreads();
  }
  // one l-reduction for the whole kernel
  float rtot = lrow;
  rtot += __shfl_xor(rtot, 16);
  rtot += __shfl_xor(rtot, 32);
#pragma unroll
  for (int r = 0; r < 4; ++r) {
    float li = __shfl(rtot, hi * 4 + r);
    float inv = 1.0f / li;
    size_t rowoff = (size_t)(qt * 64 + w * 16 + hi * 4 + r) * 2048 + h * 64;
#pragma unroll
    for (int g2 = 0; g2 < 4; ++g2)
      att[rowoff + g2 * 16 + fr] = f2bf(o[g2][r] * inv);
  }
}

extern "C" void kernel_launch(void* const* d_in, const int* in_sizes, int n_in,
                              void* d_out, int out_size, void* d_ws, size_t ws_size,
                              hipStream_t stream) {
  const float* x    = (const float*)d_in[0];
  const float* fc   = (const float*)d_in[1];
  const float* fs   = (const float*)d_in[2];
  // d_in[3] = mask (causal, regenerated in-kernel)
  const float* wq   = (const float*)d_in[4];
  const float* wq_b = (const float*)d_in[5];
  const float* wk   = (const float*)d_in[6];
  const float* wk_b = (const float*)d_in[7];
  const float* wv   = (const float*)d_in[8];
  const float* wv_b = (const float*)d_in[9];
  const float* wo   = (const float*)d_in[10];
  const float* wo_b = (const float*)d_in[11];
  const float* qn   = (const float*)d_in[12];
  const float* kn   = (const float*)d_in[13];
  float* out = (float*)d_out;

  char* ws = (char*)d_ws;
  u16*  xb    = (u16*)(ws);                          //  8 MB  x bf16 [2048][2048]
  u16*  wqkvT = (u16*)(ws + (size_t)(8  << 20));     // 12 MB  [3072][2048] bf16
  u16*  woT   = (u16*)(ws + (size_t)(20 << 20));     //  8 MB  [2048][2048] bf16
  float* qkv  = (float*)(ws + (size_t)(28 << 20));   // 24 MB  [2048][3072] f32
  u16*  Qg    = (u16*)(ws + (size_t)(52 << 20));     //  8 MB  [32][2048][64]
  u16*  Kg    = (u16*)(ws + (size_t)(60 << 20));     //  2 MB  [8][2048][64]
  u16*  Vg    = (u16*)(ws + (size_t)(62 << 20));     //  2 MB  [8][2048][64]
  u16*  att   = (u16*)(ws + (size_t)(64 << 20));     //  8 MB  [2048][2048]

  conv_bf16<<<4096, 256, 0, stream>>>(x, xb, 1048576);
  transpose_conv<<<dim3(32, 32), 256, 0, stream>>>(wq, wqkvT, 2048, 2048);
  transpose_conv<<<dim3(8, 32),  256, 0, stream>>>(wk, wqkvT + (size_t)2048 * 2048, 2048, 512);
  transpose_conv<<<dim3(8, 32),  256, 0, stream>>>(wv, wqkvT + (size_t)2560 * 2048, 2048, 512);
  transpose_conv<<<dim3(32, 32), 256, 0, stream>>>(wo, woT, 2048, 2048);
  gemm_bt<<<32 * 24, 256, 0, stream>>>(xb, wqkvT, qkv, (const float*)nullptr, 2048, 3072, 2048);
  qkv_post<<<24576, 256, 0, stream>>>(qkv, wq_b, wk_b, wv_b, qn, kn, fc, fs, Qg, Kg, Vg);
  attn_kernel<<<1024, 256, 0, stream>>>(Qg, Kg, Vg, qn, kn, att);
  gemm_bt<<<32 * 16, 256, 0, stream>>>(att, woT, out, wo_b, 2048, 2048, 2048);
}